// Round 3
// baseline (827.832 us; speedup 1.0000x reference)
//
#include <hip/hip_runtime.h>
#include <stdint.h>

#define DI __device__ __forceinline__

typedef __attribute__((ext_vector_type(8))) short short8;
typedef __attribute__((ext_vector_type(4))) float float4v;

#define MFMA16(a, b, c) __builtin_amdgcn_mfma_f32_16x16x32_bf16((a), (b), (c), 0, 0, 0)

DI float b2f(short s) {
    uint32_t u = ((uint32_t)(uint16_t)s) << 16;
    float f;
    __builtin_memcpy(&f, &u, 4);
    return f;
}
DI short f2b(float f) {
    uint32_t x;
    __builtin_memcpy(&x, &f, 4);
    x += 0x7fffu + ((x >> 16) & 1u);
    return (short)(uint16_t)(x >> 16);
}
// load 8 consecutive fp32, round-pack to bf16 short8 (MFMA operand frag)
DI short8 ld8(const float* p) {
    float4v a = *(const float4v*)p;
    float4v b = *(const float4v*)(p + 4);
    short8 r;
#pragma unroll
    for (int j = 0; j < 4; ++j) {
        r[j] = f2b(a[j]);
        r[4 + j] = f2b(b[j]);
    }
    return r;
}

// B=64, C=2048, Q=128, D=128. Global tensors fp32; MFMA operands bf16; fp32 accum.

// out[r] = dot(x[r,:], w) + (1 - mask[r]) * (-1e30).  16 lanes per row, 16 rows/block.
__global__ __launch_bounds__(256) void k_rowdotm(const float* __restrict__ x, const float* __restrict__ w,
                                                 const float* __restrict__ mask, float* __restrict__ out) {
    int tid = threadIdx.x;
    int gr = blockIdx.x * 16 + (tid >> 4);
    int sub = tid & 15;
    float4v x0 = *(const float4v*)(x + (size_t)gr * 128 + sub * 8);
    float4v x1 = *(const float4v*)(x + (size_t)gr * 128 + sub * 8 + 4);
    float4v w0 = *(const float4v*)(w + sub * 8);
    float4v w1 = *(const float4v*)(w + sub * 8 + 4);
    float s = 0.f;
#pragma unroll
    for (int j = 0; j < 4; ++j) s += x0[j] * w0[j] + x1[j] * w1[j];
#pragma unroll
    for (int off = 1; off < 16; off <<= 1) s += __shfl_xor(s, off, 64);
    if (sub == 0) out[gr] = s + (1.f - mask[gr]) * (-1e30f);
}

// qT[b,d,q] = bf16(qf[b,q,d])
__global__ __launch_bounds__(256) void k_qT(const float* __restrict__ qf, short* __restrict__ qT) {
    int b = blockIdx.x >> 6;
    int d = (blockIdx.x & 63) * 2 + (threadIdx.x >> 7);
    int q = threadIdx.x & 127;
    qT[((b * 128 + d) << 7) + q] = f2b(qf[((b * 128 + q) << 7) + d]);
}

// alpha = softmax_q(qf@wp + mask); pooled[d] = sum_q qf*alpha; pc[b,o] = cc_b[o] + sum_d pooled[d]*cc_W[o,128+d]
__global__ __launch_bounds__(128) void k_pool(const float* __restrict__ qf, const float* __restrict__ qmask,
                                              const float* __restrict__ wp, const float* __restrict__ ccW,
                                              const float* __restrict__ ccb, float* __restrict__ pc) {
    __shared__ float tmp[128], af[128], pooled[128];
    int b = blockIdx.x, t = threadIdx.x;
    const float* qrow = qf + ((size_t)(b * 128 + t) << 7);
    float s = 0.f;
    for (int d = 0; d < 128; ++d) s += qrow[d] * wp[d];
    s += (1.f - qmask[b * 128 + t]) * (-1e30f);
    tmp[t] = s;
    __syncthreads();
    for (int off = 64; off >= 1; off >>= 1) {
        if (t < off) tmp[t] = fmaxf(tmp[t], tmp[t + off]);
        __syncthreads();
    }
    float m = tmp[0];
    __syncthreads();
    float e = __expf(s - m);
    tmp[t] = e;
    __syncthreads();
    for (int off = 64; off >= 1; off >>= 1) {
        if (t < off) tmp[t] += tmp[t + off];
        __syncthreads();
    }
    af[t] = e / tmp[0];
    __syncthreads();
    float p = 0.f;
    for (int q = 0; q < 128; ++q) p += qf[((size_t)(b * 128 + q) << 7) + t] * af[q];
    pooled[t] = p;
    __syncthreads();
    float acc = ccb[t];
    for (int d = 0; d < 128; ++d) acc += pooled[d] * ccW[t * 256 + 128 + d];
    pc[b * 128 + t] = acc;
}

// Unnormalized T^T accumulation: Tf[b,d,q] += sum_{c in slab} e_t[c,q] * vf[c,d];
// colsum[b,q] += sum_c e_t[c,q].  e_t = exp(mlu_score + cv').  grid (C/128, B), 256 thr.
__global__ __launch_bounds__(256) void k_Tacc(const float* __restrict__ vf, const float* __restrict__ qf,
                                              const float* __restrict__ w4mlu, const float* __restrict__ cvp,
                                              float* __restrict__ Tf, float* __restrict__ colsum) {
    __shared__ short Al[128 * 40];  // [q][c-local]
    __shared__ short Bl[128 * 40];  // [d][c-local]
    int tid = threadIdx.x, w = tid >> 6, lane = tid & 63, ln = lane & 15, quad = lane >> 4;
    int b = blockIdx.y, c0 = blockIdx.x * 128;
    float wmf[8];
#pragma unroll
    for (int j = 0; j < 8; ++j) wmf[j] = 0.f;  // placeholder (per-ks below)
    short8 bq[2][4];
    float4v wmk[4][2];
#pragma unroll
    for (int ks = 0; ks < 4; ++ks) {
        wmk[ks][0] = *(const float4v*)(w4mlu + ks * 32 + quad * 8);
        wmk[ks][1] = *(const float4v*)(w4mlu + ks * 32 + quad * 8 + 4);
    }
#pragma unroll
    for (int y = 0; y < 2; ++y)
#pragma unroll
        for (int ks = 0; ks < 4; ++ks)
            bq[y][ks] = ld8(qf + ((size_t)(b * 128 + w * 32 + y * 16 + ln) << 7) + ks * 32 + quad * 8);
    float4v acc[2][8];
#pragma unroll
    for (int x = 0; x < 2; ++x)
#pragma unroll
        for (int dt = 0; dt < 8; ++dt) acc[x][dt] = (float4v){0.f, 0.f, 0.f, 0.f};
    float colacc[2] = {0.f, 0.f};
    for (int cc = 0; cc < 128; cc += 32) {
        int cb = c0 + cc;
        // stage Bl[d][c] = bf16(vf[cb+c, d]) transposed
        int cl = tid & 31, db = (tid >> 5) * 16;
        const float* vs = vf + ((size_t)(b * 2048 + cb + cl) << 7) + db;
#pragma unroll
        for (int g = 0; g < 4; ++g) {
            float4v v = *(const float4v*)(vs + g * 4);
#pragma unroll
            for (int i = 0; i < 4; ++i) Bl[(db + g * 4 + i) * 40 + cl] = f2b(v[i]);
        }
        // score tile 32c x 32q per wave (wave w covers q in [w*32, w*32+32))
        float4v ds[2][2];
#pragma unroll
        for (int mt = 0; mt < 2; ++mt)
#pragma unroll
            for (int y = 0; y < 2; ++y) ds[mt][y] = (float4v){0.f, 0.f, 0.f, 0.f};
#pragma unroll
        for (int ks = 0; ks < 4; ++ks) {
#pragma unroll
            for (int mt = 0; mt < 2; ++mt) {
                const float* ap = vf + ((size_t)(b * 2048 + cb + mt * 16 + ln) << 7) + ks * 32 + quad * 8;
                float4v a0 = *(const float4v*)ap;
                float4v a1 = *(const float4v*)(ap + 4);
                short8 af;
#pragma unroll
                for (int j = 0; j < 4; ++j) {
                    af[j] = f2b(a0[j] * wmk[ks][0][j]);
                    af[4 + j] = f2b(a1[j] * wmk[ks][1][j]);
                }
#pragma unroll
                for (int y = 0; y < 2; ++y) ds[mt][y] = MFMA16(af, bq[y][ks], ds[mt][y]);
            }
        }
        // e_t -> Al in A-operand layout [q][c], accumulate colsum partials
#pragma unroll
        for (int mt = 0; mt < 2; ++mt)
#pragma unroll
            for (int y = 0; y < 2; ++y)
#pragma unroll
                for (int r = 0; r < 4; ++r) {
                    int c = cb + mt * 16 + quad * 4 + r;
                    float e = __expf(ds[mt][y][r] + cvp[b * 2048 + c]);
                    Al[(w * 32 + y * 16 + ln) * 40 + mt * 16 + quad * 4 + r] = f2b(e);
                    colacc[y] += e;
                }
        __syncthreads();
        // T-GEMM: acc[x][dt] += Al[q-tile (w*2+x)] x Bl[d-tile dt] over k=c(32)
#pragma unroll
        for (int x = 0; x < 2; ++x) {
            short8 a = *(const short8*)(Al + ((w * 2 + x) * 16 + ln) * 40 + quad * 8);
#pragma unroll
            for (int dt = 0; dt < 8; ++dt) {
                short8 bb = *(const short8*)(Bl + (dt * 16 + ln) * 40 + quad * 8);
                acc[x][dt] = MFMA16(a, bb, acc[x][dt]);
            }
        }
        __syncthreads();
    }
#pragma unroll
    for (int x = 0; x < 2; ++x)
#pragma unroll
        for (int dt = 0; dt < 8; ++dt)
#pragma unroll
            for (int r = 0; r < 4; ++r) {
                int q = w * 32 + x * 16 + quad * 4 + r;
                int d = dt * 16 + ln;
                atomicAdd(&Tf[((size_t)(b * 128 + d) << 7) + q], acc[x][dt][r]);
            }
#pragma unroll
    for (int y = 0; y < 2; ++y) {
        float p = colacc[y];
        p += __shfl_xor(p, 16, 64);
        p += __shfl_xor(p, 32, 64);
        if (lane < 16) atomicAdd(&colsum[b * 128 + w * 32 + y * 16 + lane], p);
    }
}

// Tt[b,d,q] = bf16(Tf[b,d,q] / colsum[b,q])
__global__ __launch_bounds__(256) void k_Tn(const float* __restrict__ Tf, const float* __restrict__ colsum,
                                            short* __restrict__ Tt) {
    int idx = blockIdx.x * 256 + threadIdx.x;  // 64*128*128
    int b = idx >> 14, q = idx & 127;
    Tt[idx] = f2b(Tf[idx] / colsum[b * 128 + q]);
}

// Mega kernel: score tile -> row softmax -> score_ -> c2q,q2c -> cat GEMM -> out GEMM + relu.
// grid (C/64, B), 256 thr; wave w owns c-rows [bx*64 + w*16, +16).
__global__ __launch_bounds__(256) void k_out(const float* __restrict__ vf, const float* __restrict__ qf,
                                             const short* __restrict__ qT, const short* __restrict__ Tt,
                                             const float* __restrict__ qvp, const float* __restrict__ w4mlu,
                                             const float* __restrict__ cqaW, const float* __restrict__ cqab,
                                             const float* __restrict__ ccW, const float* __restrict__ pc,
                                             float* __restrict__ out) {
    __shared__ short Sl[64 * 136];   // score_ tile, later reused for feats
    __shared__ short C2l[64 * 136];  // c2q tile
    __shared__ short Q2l[64 * 136];  // q2c tile
    int tid = threadIdx.x, w = tid >> 6, lane = tid & 63, ln = lane & 15, quad = lane >> 4;
    int b = blockIdx.y, c0 = blockIdx.x * 64 + w * 16;
    size_t arow = ((size_t)(b * 2048 + c0 + ln)) << 7;  // A-frag row base (m=ln)
    // ---- score tile: 16c x 128q ----
    float4v sc[8];
#pragma unroll
    for (int qt = 0; qt < 8; ++qt) sc[qt] = (float4v){0.f, 0.f, 0.f, 0.f};
#pragma unroll
    for (int ks = 0; ks < 4; ++ks) {
        int co = ks * 32 + quad * 8;
        float4v a0 = *(const float4v*)(vf + arow + co);
        float4v a1 = *(const float4v*)(vf + arow + co + 4);
        float4v m0 = *(const float4v*)(w4mlu + co);
        float4v m1 = *(const float4v*)(w4mlu + co + 4);
        short8 af;
#pragma unroll
        for (int j = 0; j < 4; ++j) {
            af[j] = f2b(a0[j] * m0[j]);
            af[4 + j] = f2b(a1[j] * m1[j]);
        }
#pragma unroll
        for (int qt = 0; qt < 8; ++qt) {
            short8 bqf = ld8(qf + ((size_t)(b * 128 + qt * 16 + ln) << 7) + co);
            sc[qt] = MFMA16(af, bqf, sc[qt]);
        }
    }
    float qvl[8];
#pragma unroll
    for (int qt = 0; qt < 8; ++qt) qvl[qt] = qvp[b * 128 + qt * 16 + ln];
    // ---- row softmax over q (rows in C-layout: row = quad*4+r, col = qt*16+ln) ----
#pragma unroll
    for (int r = 0; r < 4; ++r) {
        float x[8], m = -3.4e38f;
#pragma unroll
        for (int qt = 0; qt < 8; ++qt) {
            x[qt] = sc[qt][r] + qvl[qt];
            m = fmaxf(m, x[qt]);
        }
#pragma unroll
        for (int off = 1; off < 16; off <<= 1) m = fmaxf(m, __shfl_xor(m, off, 64));
        float e[8], sm = 0.f;
#pragma unroll
        for (int qt = 0; qt < 8; ++qt) {
            e[qt] = __expf(x[qt] - m);
            sm += e[qt];
        }
#pragma unroll
        for (int off = 1; off < 16; off <<= 1) sm += __shfl_xor(sm, off, 64);
        float inv = 1.f / sm;
        int row = w * 16 + quad * 4 + r;
#pragma unroll
        for (int qt = 0; qt < 8; ++qt) Sl[row * 136 + qt * 16 + ln] = f2b(e[qt] * inv);
    }
    __syncthreads();
    // ---- c2q = score_ @ qf (B = qT); q2c = score_ @ T (B = Tt) ----
    float4v a2q[8], aq2[8];
#pragma unroll
    for (int dt = 0; dt < 8; ++dt) {
        a2q[dt] = (float4v){0.f, 0.f, 0.f, 0.f};
        aq2[dt] = (float4v){0.f, 0.f, 0.f, 0.f};
    }
#pragma unroll
    for (int ks = 0; ks < 4; ++ks) {
        int co = ks * 32 + quad * 8;
        short8 a = *(const short8*)(Sl + (w * 16 + ln) * 136 + co);
#pragma unroll
        for (int dt = 0; dt < 8; ++dt) {
            short8 b1 = *(const short8*)(qT + ((size_t)(b * 128 + dt * 16 + ln) << 7) + co);
            a2q[dt] = MFMA16(a, b1, a2q[dt]);
            short8 b2 = *(const short8*)(Tt + ((size_t)(b * 128 + dt * 16 + ln) << 7) + co);
            aq2[dt] = MFMA16(a, b2, aq2[dt]);
        }
    }
    __syncthreads();  // all waves done reading Sl (score_) frags
#pragma unroll
    for (int dt = 0; dt < 8; ++dt)
#pragma unroll
        for (int r = 0; r < 4; ++r) {
            int row = w * 16 + quad * 4 + r;
            C2l[row * 136 + dt * 16 + ln] = f2b(a2q[dt][r]);
            Q2l[row * 136 + dt * 16 + ln] = f2b(aq2[dt][r]);
        }
    __syncthreads();
    // ---- feats = [v, c2q, v*c2q, v*q2c] @ cqa_W.T + cqa_b ----
    float4v accF[8];
#pragma unroll
    for (int nt = 0; nt < 8; ++nt) accF[nt] = (float4v){0.f, 0.f, 0.f, 0.f};
#pragma unroll
    for (int ks = 0; ks < 4; ++ks) {
        int co = ks * 32 + quad * 8;
        float4v a0 = *(const float4v*)(vf + arow + co);
        float4v a1 = *(const float4v*)(vf + arow + co + 4);
        short8 ac = *(const short8*)(C2l + (w * 16 + ln) * 136 + co);
        short8 aq = *(const short8*)(Q2l + (w * 16 + ln) * 136 + co);
        short8 av, avc, avq;
#pragma unroll
        for (int j = 0; j < 4; ++j) {
            av[j] = f2b(a0[j]);
            av[4 + j] = f2b(a1[j]);
            avc[j] = f2b(a0[j] * b2f(ac[j]));
            avc[4 + j] = f2b(a1[j] * b2f(ac[4 + j]));
            avq[j] = f2b(a0[j] * b2f(aq[j]));
            avq[4 + j] = f2b(a1[j] * b2f(aq[4 + j]));
        }
        short8 parts[4] = {av, ac, avc, avq};
#pragma unroll
        for (int part = 0; part < 4; ++part) {
#pragma unroll
            for (int nt = 0; nt < 8; ++nt) {
                short8 bw = ld8(cqaW + (size_t)(nt * 16 + ln) * 512 + part * 128 + co);
                accF[nt] = MFMA16(parts[part], bw, accF[nt]);
            }
        }
    }
    __syncthreads();  // done reading Sl as score_ before overwrite with feats
#pragma unroll
    for (int nt = 0; nt < 8; ++nt) {
        int j = nt * 16 + ln;
        float bj = cqab[j];
#pragma unroll
        for (int r = 0; r < 4; ++r) Sl[(w * 16 + quad * 4 + r) * 136 + j] = f2b(accF[nt][r] + bj);
    }
    __syncthreads();
    // ---- out = relu(feats @ ccW[:, :128].T + pc) ----
    float4v accO[8];
#pragma unroll
    for (int ot = 0; ot < 8; ++ot) accO[ot] = (float4v){0.f, 0.f, 0.f, 0.f};
#pragma unroll
    for (int ks = 0; ks < 4; ++ks) {
        int co = ks * 32 + quad * 8;
        short8 a2 = *(const short8*)(Sl + (w * 16 + ln) * 136 + co);
#pragma unroll
        for (int ot = 0; ot < 8; ++ot) {
            short8 bw = ld8(ccW + (size_t)(ot * 16 + ln) * 256 + co);
            accO[ot] = MFMA16(a2, bw, accO[ot]);
        }
    }
#pragma unroll
    for (int ot = 0; ot < 8; ++ot) {
        int o = ot * 16 + ln;
        float pco = pc[b * 128 + o];
#pragma unroll
        for (int r = 0; r < 4; ++r) {
            int c = c0 + quad * 4 + r;
            out[((size_t)(b * 2048 + c) << 7) + o] = fmaxf(accO[ot][r] + pco, 0.f);
        }
    }
}

extern "C" void kernel_launch(void* const* d_in, const int* in_sizes, int n_in, void* d_out, int out_size, void* d_ws,
                              size_t ws_size, hipStream_t stream) {
    const float* vf = (const float*)d_in[0];
    const float* qf = (const float*)d_in[1];
    const float* vmask = (const float*)d_in[2];
    const float* qmask = (const float*)d_in[3];
    const float* w4C = (const float*)d_in[4];
    const float* w4Q = (const float*)d_in[5];
    const float* w4mlu = (const float*)d_in[6];
    const float* cqaW = (const float*)d_in[7];
    const float* cqab = (const float*)d_in[8];
    const float* wp = (const float*)d_in[9];
    const float* ccW = (const float*)d_in[10];
    const float* ccb = (const float*)d_in[11];
    float* out = (float*)d_out;
    char* ws = (char*)d_ws;

    // workspace layout (total ~8.6 MB)
    size_t oQT = 0;                             // [B,D,Q] bf16: 2 MB
    size_t oTt = oQT + 64ull * 128 * 128 * 2;   // [B,D,Q] bf16: 2 MB
    size_t oTf = oTt + 64ull * 128 * 128 * 2;   // [B,D,Q] f32: 4 MB
    size_t oCv = oTf + 64ull * 128 * 128 * 4;   // [B,C] f32: 512 KB
    size_t oQv = oCv + 64ull * 2048 * 4;        // [B,Q] f32: 32 KB
    size_t oCs = oQv + 64ull * 128 * 4;         // [B,Q] f32: 32 KB
    size_t oPc = oCs + 64ull * 128 * 4;         // [B,D] f32: 32 KB

    short* qT = (short*)(ws + oQT);
    short* Tt = (short*)(ws + oTt);
    float* Tf = (float*)(ws + oTf);
    float* cvp = (float*)(ws + oCv);
    float* qvp = (float*)(ws + oQv);
    float* colsum = (float*)(ws + oCs);
    float* pc = (float*)(ws + oPc);

    hipMemsetAsync(Tf, 0, 64ull * 128 * 128 * 4, stream);
    hipMemsetAsync(colsum, 0, 64ull * 128 * 4, stream);

    k_rowdotm<<<8192, 256, 0, stream>>>(vf, w4C, vmask, cvp);
    k_rowdotm<<<512, 256, 0, stream>>>(qf, w4Q, qmask, qvp);
    k_qT<<<4096, 256, 0, stream>>>(qf, qT);
    k_pool<<<64, 128, 0, stream>>>(qf, qmask, wp, ccW, ccb, pc);
    k_Tacc<<<dim3(16, 64), 256, 0, stream>>>(vf, qf, w4mlu, cvp, Tf, colsum);
    k_Tn<<<4096, 256, 0, stream>>>(Tf, colsum, Tt);
    k_out<<<dim3(32, 64), 256, 0, stream>>>(vf, qf, qT, Tt, qvp, w4mlu, cqaW, cqab, ccW, pc, out);
}

// Round 4
// 491.774 us; speedup vs baseline: 1.6834x; 1.6834x over previous
//
#include <hip/hip_runtime.h>
#include <stdint.h>

#define DI __device__ __forceinline__

typedef __attribute__((ext_vector_type(8))) short short8;
typedef __attribute__((ext_vector_type(4))) float float4v;

#define MFMA16(a, b, c) __builtin_amdgcn_mfma_f32_16x16x32_bf16((a), (b), (c), 0, 0, 0)

DI float b2f(short s) {
    uint32_t u = ((uint32_t)(uint16_t)s) << 16;
    float f;
    __builtin_memcpy(&f, &u, 4);
    return f;
}
DI short f2b(float f) {
    uint32_t x;
    __builtin_memcpy(&x, &f, 4);
    x += 0x7fffu + ((x >> 16) & 1u);
    return (short)(uint16_t)(x >> 16);
}

// B=64, C=2048, Q=128, D=128. Frag layout: frag_id*512 + lane*8 (+j), bf16.
// A/B frag element mapping (verified in R3): row = tile*16 + (lane&15), col = ks*32 + (lane>>4)*8 + j.

// Pack row-major fp32 [tiles*16 x 128] -> frag tiles. One block per 16-row tile.
__global__ __launch_bounds__(256) void k_packrows(const float* __restrict__ src, short* __restrict__ dst) {
    int tile = blockIdx.x, t = threadIdx.x;
    int r = t >> 4, c16 = t & 15;  // c16*8 = ks*32 + quad*8
    int ks = c16 >> 2, quad = c16 & 3;
    const float* p = src + ((size_t)(tile * 16 + r) << 7) + c16 * 8;
    float4v a = *(const float4v*)p, b = *(const float4v*)(p + 4);
    short8 v;
#pragma unroll
    for (int j = 0; j < 4; ++j) {
        v[j] = f2b(a[j]);
        v[4 + j] = f2b(b[j]);
    }
    *(short8*)(dst + ((size_t)(tile * 4 + ks) << 9) + (quad * 16 + r) * 8) = v;
}

// Transpose-pack qf [B][Q][D] fp32 -> qTf frags: frag (b*8+dt)*4+ks, element = qf[b][q][d], d=row, q=col.
__global__ __launch_bounds__(256) void k_packT(const float* __restrict__ qf, short* __restrict__ dst) {
    int idx = blockIdx.x * 256 + threadIdx.x;  // 131072
    int lane = idx & 63, ks = (idx >> 6) & 3, dtb = idx >> 8;
    int dt = dtb & 7, b = dtb >> 3;
    int d = dt * 16 + (lane & 15), q0 = ks * 32 + (lane >> 4) * 8;
    short8 v;
#pragma unroll
    for (int e = 0; e < 8; ++e) v[e] = f2b(qf[((size_t)(b * 128 + q0 + e) << 7) + d]);
    *(short8*)(dst + (size_t)idx * 8) = v;
}

// Pack cqa_W [128][512] fp32 -> frags ((nt*4+part)*4+ks).
__global__ __launch_bounds__(256) void k_packW(const float* __restrict__ wsrc, short* __restrict__ dst) {
    int idx = blockIdx.x * 256 + threadIdx.x;  // 8192
    int lane = idx & 63, ks = (idx >> 6) & 3, part = (idx >> 8) & 3, nt = idx >> 10;
    const float* p = wsrc + (size_t)(nt * 16 + (lane & 15)) * 512 + part * 128 + ks * 32 + (lane >> 4) * 8;
    float4v a = *(const float4v*)p, b = *(const float4v*)(p + 4);
    short8 v;
#pragma unroll
    for (int j = 0; j < 4; ++j) {
        v[j] = f2b(a[j]);
        v[4 + j] = f2b(b[j]);
    }
    *(short8*)(dst + (size_t)idx * 8) = v;
}

// Pack cc_W[:, :128] ([128][256] fp32) -> frags (ot*4+ks).
__global__ __launch_bounds__(256) void k_packWc(const float* __restrict__ wsrc, short* __restrict__ dst) {
    int idx = blockIdx.x * 256 + threadIdx.x;  // 2048
    int lane = idx & 63, ks = (idx >> 6) & 3, ot = idx >> 8;
    const float* p = wsrc + (size_t)(ot * 16 + (lane & 15)) * 256 + ks * 32 + (lane >> 4) * 8;
    float4v a = *(const float4v*)p, b = *(const float4v*)(p + 4);
    short8 v;
#pragma unroll
    for (int j = 0; j < 4; ++j) {
        v[j] = f2b(a[j]);
        v[4 + j] = f2b(b[j]);
    }
    *(short8*)(dst + (size_t)idx * 8) = v;
}

// out[r] = dot(x[r,:], w) + (1 - mask[r]) * (-1e30)
__global__ __launch_bounds__(256) void k_rowdotm(const float* __restrict__ x, const float* __restrict__ w,
                                                 const float* __restrict__ mask, float* __restrict__ out) {
    int tid = threadIdx.x;
    int gr = blockIdx.x * 16 + (tid >> 4);
    int sub = tid & 15;
    float4v x0 = *(const float4v*)(x + (size_t)gr * 128 + sub * 8);
    float4v x1 = *(const float4v*)(x + (size_t)gr * 128 + sub * 8 + 4);
    float4v w0 = *(const float4v*)(w + sub * 8);
    float4v w1 = *(const float4v*)(w + sub * 8 + 4);
    float s = 0.f;
#pragma unroll
    for (int j = 0; j < 4; ++j) s += x0[j] * w0[j] + x1[j] * w1[j];
#pragma unroll
    for (int off = 1; off < 16; off <<= 1) s += __shfl_xor(s, off, 64);
    if (sub == 0) out[gr] = s + (1.f - mask[gr]) * (-1e30f);
}

// alpha = softmax_q(qf@wp + mask); pooled[d] = sum_q qf*alpha; pc[b,o] = cc_b[o] + sum_d pooled[d]*cc_W[o,128+d]
__global__ __launch_bounds__(128) void k_pool(const float* __restrict__ qf, const float* __restrict__ qmask,
                                              const float* __restrict__ wp, const float* __restrict__ ccW,
                                              const float* __restrict__ ccb, float* __restrict__ pc) {
    __shared__ float tmp[128], af[128], pooled[128];
    int b = blockIdx.x, t = threadIdx.x;
    const float* qrow = qf + ((size_t)(b * 128 + t) << 7);
    float s = 0.f;
    for (int d = 0; d < 128; ++d) s += qrow[d] * wp[d];
    s += (1.f - qmask[b * 128 + t]) * (-1e30f);
    tmp[t] = s;
    __syncthreads();
    for (int off = 64; off >= 1; off >>= 1) {
        if (t < off) tmp[t] = fmaxf(tmp[t], tmp[t + off]);
        __syncthreads();
    }
    float m = tmp[0];
    __syncthreads();
    float e = __expf(s - m);
    tmp[t] = e;
    __syncthreads();
    for (int off = 64; off >= 1; off >>= 1) {
        if (t < off) tmp[t] += tmp[t + off];
        __syncthreads();
    }
    af[t] = e / tmp[0];
    __syncthreads();
    float p = 0.f;
    for (int q = 0; q < 128; ++q) p += qf[((size_t)(b * 128 + q) << 7) + t] * af[q];
    pooled[t] = p;
    __syncthreads();
    float acc = ccb[t];
    for (int d = 0; d < 128; ++d) acc += pooled[d] * ccW[t * 256 + 128 + d];
    pc[b * 128 + t] = acc;
}

// Unnormalized T^T accumulation, all operands from frag-packed buffers. grid (C/128, B).
__global__ __launch_bounds__(256) void k_Tacc(const short* __restrict__ vfA, const short* __restrict__ qfB,
                                              const float* __restrict__ w4mlu, const float* __restrict__ cvp,
                                              float* __restrict__ Tf, float* __restrict__ colsum) {
    __shared__ short Al[128 * 40];  // [q][c-local]
    __shared__ short Bl[128 * 40];  // [d][c-local]
    int tid = threadIdx.x, w = tid >> 6, lane = tid & 63, ln = lane & 15, quad = lane >> 4;
    int b = blockIdx.y, c0 = blockIdx.x * 128;
    float wmk[4][8];
#pragma unroll
    for (int ks = 0; ks < 4; ++ks)
#pragma unroll
        for (int j = 0; j < 8; ++j) wmk[ks][j] = w4mlu[ks * 32 + quad * 8 + j];
    short8 bq[2][4];
#pragma unroll
    for (int y = 0; y < 2; ++y)
#pragma unroll
        for (int ks = 0; ks < 4; ++ks)
            bq[y][ks] = *(const short8*)(qfB + (((size_t)(b * 8 + w * 2 + y) * 4 + ks) << 9) + lane * 8);
    float4v acc[2][8];
#pragma unroll
    for (int x = 0; x < 2; ++x)
#pragma unroll
        for (int dt = 0; dt < 8; ++dt) acc[x][dt] = (float4v){0.f, 0.f, 0.f, 0.f};
    float colacc[2] = {0.f, 0.f};
    for (int cc = 0; cc < 128; cc += 32) {
        int cb = c0 + cc;
        int tt0 = b * 128 + (cb >> 4);
        // stage Bl[d][c_local] from vfA (coalesced reads, scattered LDS writes)
#pragma unroll
        for (int it = 0; it < 2; ++it) {
            int flat = tid + 256 * it;  // 512
            int l = flat & 63, ksf = (flat >> 6) & 3, mtf = flat >> 8;
            short8 v = *(const short8*)(vfA + (((size_t)(tt0 + mtf) * 4 + ksf) << 9) + l * 8);
            int cl = mtf * 16 + (l & 15), d = ksf * 32 + (l >> 4) * 8;
#pragma unroll
            for (int i = 0; i < 8; ++i) Bl[(d + i) * 40 + cl] = v[i];
        }
        // score tile 32c x 32q per wave
        float4v ds[2][2];
#pragma unroll
        for (int mt = 0; mt < 2; ++mt)
#pragma unroll
            for (int y = 0; y < 2; ++y) ds[mt][y] = (float4v){0.f, 0.f, 0.f, 0.f};
#pragma unroll
        for (int ks = 0; ks < 4; ++ks) {
#pragma unroll
            for (int mt = 0; mt < 2; ++mt) {
                short8 av = *(const short8*)(vfA + (((size_t)(tt0 + mt) * 4 + ks) << 9) + lane * 8);
                short8 af;
#pragma unroll
                for (int j = 0; j < 8; ++j) af[j] = f2b(b2f(av[j]) * wmk[ks][j]);
#pragma unroll
                for (int y = 0; y < 2; ++y) ds[mt][y] = MFMA16(af, bq[y][ks], ds[mt][y]);
            }
        }
        // e_t -> Al (A layout [q][c]), colsum partials
#pragma unroll
        for (int mt = 0; mt < 2; ++mt)
#pragma unroll
            for (int y = 0; y < 2; ++y)
#pragma unroll
                for (int r = 0; r < 4; ++r) {
                    int c = cb + mt * 16 + quad * 4 + r;
                    float e = __expf(ds[mt][y][r] + cvp[b * 2048 + c]);
                    Al[(w * 32 + y * 16 + ln) * 40 + mt * 16 + quad * 4 + r] = f2b(e);
                    colacc[y] += e;
                }
        __syncthreads();
#pragma unroll
        for (int x = 0; x < 2; ++x) {
            short8 a = *(const short8*)(Al + ((w * 2 + x) * 16 + ln) * 40 + quad * 8);
#pragma unroll
            for (int dt = 0; dt < 8; ++dt) {
                short8 bb = *(const short8*)(Bl + (dt * 16 + ln) * 40 + quad * 8);
                acc[x][dt] = MFMA16(a, bb, acc[x][dt]);
            }
        }
        __syncthreads();
    }
#pragma unroll
    for (int x = 0; x < 2; ++x)
#pragma unroll
        for (int dt = 0; dt < 8; ++dt)
#pragma unroll
            for (int r = 0; r < 4; ++r) {
                int q = w * 32 + x * 16 + quad * 4 + r;
                int d = dt * 16 + ln;
                atomicAdd(&Tf[((size_t)(b * 128 + d) << 7) + q], acc[x][dt][r]);
            }
#pragma unroll
    for (int y = 0; y < 2; ++y) {
        float p = colacc[y];
        p += __shfl_xor(p, 16, 64);
        p += __shfl_xor(p, 32, 64);
        if (lane < 16) atomicAdd(&colsum[b * 128 + w * 32 + y * 16 + lane], p);
    }
}

// Ttf frag = bf16(Tf[b,d,q] / colsum[b,q]) in frag layout matching k_out's q2c B-read.
__global__ __launch_bounds__(256) void k_Tn(const float* __restrict__ Tf, const float* __restrict__ colsum,
                                            short* __restrict__ Ttf) {
    int idx = blockIdx.x * 256 + threadIdx.x;  // 131072
    int lane = idx & 63, ks = (idx >> 6) & 3, dtb = idx >> 8;
    int dt = dtb & 7, b = dtb >> 3;
    int d = dt * 16 + (lane & 15), q0 = ks * 32 + (lane >> 4) * 8;
    const float* p = Tf + ((size_t)(b * 128 + d) << 7) + q0;
    float4v t0 = *(const float4v*)p, t1 = *(const float4v*)(p + 4);
    const float* cs = colsum + b * 128 + q0;
    float4v c0 = *(const float4v*)cs, c1 = *(const float4v*)(cs + 4);
    short8 v;
#pragma unroll
    for (int j = 0; j < 4; ++j) {
        v[j] = f2b(t0[j] / c0[j]);
        v[4 + j] = f2b(t1[j] / c1[j]);
    }
    *(short8*)(Ttf + (size_t)idx * 8) = v;
}

// Mega kernel, all frag-packed operands. grid (C/64, B), 256 thr.
__global__ __launch_bounds__(256) void k_out(const short* __restrict__ vfA, const short* __restrict__ qfB,
                                             const short* __restrict__ qTf, const short* __restrict__ Ttf,
                                             const float* __restrict__ qvp, const float* __restrict__ w4mlu,
                                             const short* __restrict__ cqaWp, const float* __restrict__ cqab,
                                             const short* __restrict__ ccWp, const float* __restrict__ pc,
                                             float* __restrict__ out) {
    __shared__ short Sl[64 * 136];   // score_, later feats
    __shared__ short C2l[64 * 136];  // c2q
    __shared__ short Q2l[64 * 136];  // q2c
    int tid = threadIdx.x, w = tid >> 6, lane = tid & 63, ln = lane & 15, quad = lane >> 4;
    int b = blockIdx.y, c0 = blockIdx.x * 64 + w * 16;
    int tt = b * 128 + (c0 >> 4);
    // ---- score tile: 16c x 128q ----
    short8 av[4];
    float4v sc[8];
#pragma unroll
    for (int qt = 0; qt < 8; ++qt) sc[qt] = (float4v){0.f, 0.f, 0.f, 0.f};
#pragma unroll
    for (int ks = 0; ks < 4; ++ks) {
        av[ks] = *(const short8*)(vfA + (((size_t)tt * 4 + ks) << 9) + lane * 8);
        short8 af;
#pragma unroll
        for (int j = 0; j < 8; ++j) af[j] = f2b(b2f(av[ks][j]) * w4mlu[ks * 32 + quad * 8 + j]);
#pragma unroll
        for (int qt = 0; qt < 8; ++qt) {
            short8 bq = *(const short8*)(qfB + (((size_t)(b * 8 + qt) * 4 + ks) << 9) + lane * 8);
            sc[qt] = MFMA16(af, bq, sc[qt]);
        }
    }
    float qvl[8];
#pragma unroll
    for (int qt = 0; qt < 8; ++qt) qvl[qt] = qvp[b * 128 + qt * 16 + ln];
    // ---- row softmax over q (C-layout rows: quad*4+r; cols qt*16+ln) ----
#pragma unroll
    for (int r = 0; r < 4; ++r) {
        float x[8], m = -3.4e38f;
#pragma unroll
        for (int qt = 0; qt < 8; ++qt) {
            x[qt] = sc[qt][r] + qvl[qt];
            m = fmaxf(m, x[qt]);
        }
#pragma unroll
        for (int off = 1; off < 16; off <<= 1) m = fmaxf(m, __shfl_xor(m, off, 64));
        float e[8], sm = 0.f;
#pragma unroll
        for (int qt = 0; qt < 8; ++qt) {
            e[qt] = __expf(x[qt] - m);
            sm += e[qt];
        }
#pragma unroll
        for (int off = 1; off < 16; off <<= 1) sm += __shfl_xor(sm, off, 64);
        float inv = 1.f / sm;
        int row = w * 16 + quad * 4 + r;
#pragma unroll
        for (int qt = 0; qt < 8; ++qt) Sl[row * 136 + qt * 16 + ln] = f2b(e[qt] * inv);
    }
    __syncthreads();
    // ---- c2q = score_ @ qf ; q2c = score_ @ T ----
    float4v a2q[8], aq2[8];
#pragma unroll
    for (int dt = 0; dt < 8; ++dt) {
        a2q[dt] = (float4v){0.f, 0.f, 0.f, 0.f};
        aq2[dt] = (float4v){0.f, 0.f, 0.f, 0.f};
    }
#pragma unroll
    for (int ks = 0; ks < 4; ++ks) {
        short8 a = *(const short8*)(Sl + (w * 16 + ln) * 136 + ks * 32 + quad * 8);
#pragma unroll
        for (int dt = 0; dt < 8; ++dt) {
            short8 b1 = *(const short8*)(qTf + (((size_t)(b * 8 + dt) * 4 + ks) << 9) + lane * 8);
            a2q[dt] = MFMA16(a, b1, a2q[dt]);
            short8 b2 = *(const short8*)(Ttf + (((size_t)(b * 8 + dt) * 4 + ks) << 9) + lane * 8);
            aq2[dt] = MFMA16(a, b2, aq2[dt]);
        }
    }
    __syncthreads();
#pragma unroll
    for (int dt = 0; dt < 8; ++dt)
#pragma unroll
        for (int r = 0; r < 4; ++r) {
            int row = w * 16 + quad * 4 + r;
            C2l[row * 136 + dt * 16 + ln] = f2b(a2q[dt][r]);
            Q2l[row * 136 + dt * 16 + ln] = f2b(aq2[dt][r]);
        }
    __syncthreads();
    // ---- feats = [v, c2q, v*c2q, v*q2c] @ cqa_W.T + cqa_b ----
    float4v accF[8];
#pragma unroll
    for (int nt = 0; nt < 8; ++nt) accF[nt] = (float4v){0.f, 0.f, 0.f, 0.f};
#pragma unroll
    for (int ks = 0; ks < 4; ++ks) {
        int co = ks * 32 + quad * 8;
        short8 ac = *(const short8*)(C2l + (w * 16 + ln) * 136 + co);
        short8 aq = *(const short8*)(Q2l + (w * 16 + ln) * 136 + co);
        short8 avc, avq;
#pragma unroll
        for (int j = 0; j < 8; ++j) {
            float fv = b2f(av[ks][j]);
            avc[j] = f2b(fv * b2f(ac[j]));
            avq[j] = f2b(fv * b2f(aq[j]));
        }
        short8 parts[4] = {av[ks], ac, avc, avq};
#pragma unroll
        for (int part = 0; part < 4; ++part) {
#pragma unroll
            for (int nt = 0; nt < 8; ++nt) {
                short8 bw = *(const short8*)(cqaWp + (((size_t)(nt * 4 + part) * 4 + ks) << 9) + lane * 8);
                accF[nt] = MFMA16(parts[part], bw, accF[nt]);
            }
        }
    }
    __syncthreads();  // done reading Sl as score_
#pragma unroll
    for (int nt = 0; nt < 8; ++nt) {
        int j = nt * 16 + ln;
        float bj = cqab[j];
#pragma unroll
        for (int r = 0; r < 4; ++r) Sl[(w * 16 + quad * 4 + r) * 136 + j] = f2b(accF[nt][r] + bj);
    }
    __syncthreads();
    // ---- out = relu(feats @ ccW[:, :128].T + pc) ----
    float4v accO[8];
#pragma unroll
    for (int ot = 0; ot < 8; ++ot) accO[ot] = (float4v){0.f, 0.f, 0.f, 0.f};
#pragma unroll
    for (int ks = 0; ks < 4; ++ks) {
        short8 a2 = *(const short8*)(Sl + (w * 16 + ln) * 136 + ks * 32 + quad * 8);
#pragma unroll
        for (int ot = 0; ot < 8; ++ot) {
            short8 bw = *(const short8*)(ccWp + (((size_t)(ot * 4 + ks)) << 9) + lane * 8);
            accO[ot] = MFMA16(a2, bw, accO[ot]);
        }
    }
#pragma unroll
    for (int ot = 0; ot < 8; ++ot) {
        int o = ot * 16 + ln;
        float pco = pc[b * 128 + o];
#pragma unroll
        for (int r = 0; r < 4; ++r) {
            int c = c0 + quad * 4 + r;
            out[((size_t)(b * 2048 + c) << 7) + o] = fmaxf(accO[ot][r] + pco, 0.f);
        }
    }
}

extern "C" void kernel_launch(void* const* d_in, const int* in_sizes, int n_in, void* d_out, int out_size, void* d_ws,
                              size_t ws_size, hipStream_t stream) {
    const float* vf = (const float*)d_in[0];
    const float* qf = (const float*)d_in[1];
    const float* vmask = (const float*)d_in[2];
    const float* qmask = (const float*)d_in[3];
    const float* w4C = (const float*)d_in[4];
    const float* w4Q = (const float*)d_in[5];
    const float* w4mlu = (const float*)d_in[6];
    const float* cqaW = (const float*)d_in[7];
    const float* cqab = (const float*)d_in[8];
    const float* wp = (const float*)d_in[9];
    const float* ccW = (const float*)d_in[10];
    const float* ccb = (const float*)d_in[11];
    float* out = (float*)d_out;
    char* ws = (char*)d_ws;

    // workspace layout (~44.8 MB)
    size_t o = 0;
    short* vfA = (short*)(ws + o); o += 64ull * 2048 * 128 * 2;   // 33.5 MB
    short* qfB = (short*)(ws + o); o += 64ull * 128 * 128 * 2;    // 2 MB
    short* qTf = (short*)(ws + o); o += 64ull * 128 * 128 * 2;    // 2 MB
    short* Ttf = (short*)(ws + o); o += 64ull * 128 * 128 * 2;    // 2 MB
    short* cqaWp = (short*)(ws + o); o += 128ull * 512 * 2;       // 128 KB
    short* ccWp = (short*)(ws + o); o += 128ull * 128 * 2;        // 32 KB
    float* Tf = (float*)(ws + o); o += 64ull * 128 * 128 * 4;     // 4 MB
    float* cvp = (float*)(ws + o); o += 64ull * 2048 * 4;         // 512 KB
    float* qvp = (float*)(ws + o); o += 64ull * 128 * 4;
    float* colsum = (float*)(ws + o); o += 64ull * 128 * 4;
    float* pc = (float*)(ws + o); o += 64ull * 128 * 4;

    hipMemsetAsync(Tf, 0, 64ull * 128 * 128 * 4, stream);
    hipMemsetAsync(colsum, 0, 64ull * 128 * 4, stream);

    k_packrows<<<8192, 256, 0, stream>>>(vf, vfA);
    k_packrows<<<512, 256, 0, stream>>>(qf, qfB);
    k_packT<<<512, 256, 0, stream>>>(qf, qTf);
    k_packW<<<32, 256, 0, stream>>>(cqaW, cqaWp);
    k_packWc<<<8, 256, 0, stream>>>(ccW, ccWp);
    k_rowdotm<<<8192, 256, 0, stream>>>(vf, w4C, vmask, cvp);
    k_rowdotm<<<512, 256, 0, stream>>>(qf, w4Q, qmask, qvp);
    k_pool<<<64, 128, 0, stream>>>(qf, qmask, wp, ccW, ccb, pc);
    k_Tacc<<<dim3(16, 64), 256, 0, stream>>>(vfA, qfB, w4mlu, cvp, Tf, colsum);
    k_Tn<<<512, 256, 0, stream>>>(Tf, colsum, Ttf);
    k_out<<<dim3(32, 64), 256, 0, stream>>>(vfA, qfB, qTf, Ttf, qvp, w4mlu, cqaWp, cqab, ccWp, pc, out);
}

// Round 5
// 417.771 us; speedup vs baseline: 1.9815x; 1.1771x over previous
//
#include <hip/hip_runtime.h>
#include <stdint.h>

#define DI __device__ __forceinline__

typedef __attribute__((ext_vector_type(8))) short short8;
typedef __attribute__((ext_vector_type(4))) short short4v;
typedef __attribute__((ext_vector_type(4))) float float4v;

#define MFMA16(a, b, c) __builtin_amdgcn_mfma_f32_16x16x32_bf16((a), (b), (c), 0, 0, 0)

DI float b2f(short s) {
    uint32_t u = ((uint32_t)(uint16_t)s) << 16;
    float f;
    __builtin_memcpy(&f, &u, 4);
    return f;
}
DI short f2b(float f) {
    uint32_t x;
    __builtin_memcpy(&x, &f, 4);
    x += 0x7fffu + ((x >> 16) & 1u);
    return (short)(uint16_t)(x >> 16);
}

// B=64, C=2048, Q=128, D=128. Frag layout: frag_id*512 + lane*8 (+j), bf16.
// A/B frag mapping: row = tile*16 + (lane&15), col(k) = ks*32 + (lane>>4)*8 + j.

// Pack row-major fp32 [tiles*16 x 128] -> frag tiles, fused row-dot (cv/qv).
__global__ __launch_bounds__(256) void k_packrows_dot(const float* __restrict__ src, const float* __restrict__ wv,
                                                      const float* __restrict__ mask, short* __restrict__ dst,
                                                      float* __restrict__ dotout) {
    int tile = blockIdx.x, t = threadIdx.x;
    int r = t >> 4, c16 = t & 15;
    int ks = c16 >> 2, quad = c16 & 3;
    const float* p = src + ((size_t)(tile * 16 + r) << 7) + c16 * 8;
    float4v a = *(const float4v*)p, b = *(const float4v*)(p + 4);
    float4v w0 = *(const float4v*)(wv + c16 * 8), w1 = *(const float4v*)(wv + c16 * 8 + 4);
    short8 v;
    float s = 0.f;
#pragma unroll
    for (int j = 0; j < 4; ++j) {
        v[j] = f2b(a[j]);
        v[4 + j] = f2b(b[j]);
        s += a[j] * w0[j] + b[j] * w1[j];
    }
    *(short8*)(dst + ((size_t)(tile * 4 + ks) << 9) + (quad * 16 + r) * 8) = v;
#pragma unroll
    for (int off = 1; off < 16; off <<= 1) s += __shfl_xor(s, off, 64);
    if (c16 == 0) {
        int gr = tile * 16 + r;
        dotout[gr] = s + (1.f - mask[gr]) * (-1e30f);
    }
}

// Same but multiplies packed values by w4mlu (score B operand: w∘q); dot still uses raw values.
__global__ __launch_bounds__(256) void k_packrowsW_dot(const float* __restrict__ src, const float* __restrict__ wm,
                                                       const float* __restrict__ wv, const float* __restrict__ mask,
                                                       short* __restrict__ dst, float* __restrict__ dotout) {
    int tile = blockIdx.x, t = threadIdx.x;
    int r = t >> 4, c16 = t & 15;
    int ks = c16 >> 2, quad = c16 & 3;
    const float* p = src + ((size_t)(tile * 16 + r) << 7) + c16 * 8;
    float4v a = *(const float4v*)p, b = *(const float4v*)(p + 4);
    float4v w0 = *(const float4v*)(wv + c16 * 8), w1 = *(const float4v*)(wv + c16 * 8 + 4);
    float4v m0 = *(const float4v*)(wm + c16 * 8), m1 = *(const float4v*)(wm + c16 * 8 + 4);
    short8 v;
    float s = 0.f;
#pragma unroll
    for (int j = 0; j < 4; ++j) {
        v[j] = f2b(a[j] * m0[j]);
        v[4 + j] = f2b(b[j] * m1[j]);
        s += a[j] * w0[j] + b[j] * w1[j];
    }
    *(short8*)(dst + ((size_t)(tile * 4 + ks) << 9) + (quad * 16 + r) * 8) = v;
#pragma unroll
    for (int off = 1; off < 16; off <<= 1) s += __shfl_xor(s, off, 64);
    if (c16 == 0) {
        int gr = tile * 16 + r;
        dotout[gr] = s + (1.f - mask[gr]) * (-1e30f);
    }
}

// Transpose-pack src [b][rows=nkc*32][128] fp32 -> B-frags over (n=col d, k=row):
// frag ((b*8+dt)*nkc + kc), element row d = dt*16+(lane&15), col k = kc*32+(lane>>4)*8+j.
__global__ __launch_bounds__(256) void k_packTv(const float* __restrict__ src, short* __restrict__ dst, int nkc) {
    __shared__ float St[32 * 133];
    int t = threadIdx.x, kc = blockIdx.x, b = blockIdx.y;
    int rl = t >> 3, dseg = (t & 7) * 16;
    const float* p = src + ((size_t)((b * nkc + kc) * 32 + rl) << 7) + dseg;
#pragma unroll
    for (int g = 0; g < 4; ++g) {
        float4v v = *(const float4v*)(p + g * 4);
#pragma unroll
        for (int j = 0; j < 4; ++j) St[rl * 133 + dseg + g * 4 + j] = v[j];
    }
    __syncthreads();
#pragma unroll
    for (int i = 0; i < 2; ++i) {
        int dt = (t >> 6) + i * 4;
        int lane = t & 63, ln = lane & 15, quad = lane >> 4;
        int d = dt * 16 + ln;
        short8 v;
#pragma unroll
        for (int j = 0; j < 8; ++j) v[j] = f2b(St[(quad * 8 + j) * 133 + d]);
        *(short8*)(dst + (((size_t)(b * 8 + dt) * nkc + kc) << 9) + lane * 8) = v;
    }
}

// Pack cqa_W [128][512] fp32 -> frags ((nt*4+part)*4+ks).
__global__ __launch_bounds__(256) void k_packW(const float* __restrict__ wsrc, short* __restrict__ dst) {
    int idx = blockIdx.x * 256 + threadIdx.x;  // 8192
    int lane = idx & 63, ks = (idx >> 6) & 3, part = (idx >> 8) & 3, nt = idx >> 10;
    const float* p = wsrc + (size_t)(nt * 16 + (lane & 15)) * 512 + part * 128 + ks * 32 + (lane >> 4) * 8;
    float4v a = *(const float4v*)p, b = *(const float4v*)(p + 4);
    short8 v;
#pragma unroll
    for (int j = 0; j < 4; ++j) {
        v[j] = f2b(a[j]);
        v[4 + j] = f2b(b[j]);
    }
    *(short8*)(dst + (size_t)idx * 8) = v;
}

// Pack cc_W[:, :128] ([128][256] fp32) -> frags (ot*4+ks).
__global__ __launch_bounds__(256) void k_packWc(const float* __restrict__ wsrc, short* __restrict__ dst) {
    int idx = blockIdx.x * 256 + threadIdx.x;  // 2048
    int lane = idx & 63, ks = (idx >> 6) & 3, ot = idx >> 8;
    const float* p = wsrc + (size_t)(ot * 16 + (lane & 15)) * 256 + ks * 32 + (lane >> 4) * 8;
    float4v a = *(const float4v*)p, b = *(const float4v*)(p + 4);
    short8 v;
#pragma unroll
    for (int j = 0; j < 4; ++j) {
        v[j] = f2b(a[j]);
        v[4 + j] = f2b(b[j]);
    }
    *(short8*)(dst + (size_t)idx * 8) = v;
}

// alpha = softmax_q(qf@wp + mask); pooled[d] = sum_q qf*alpha; pc[b,o] = cc_b[o] + sum_d pooled[d]*cc_W[o,128+d]
__global__ __launch_bounds__(128) void k_pool(const float* __restrict__ qf, const float* __restrict__ qmask,
                                              const float* __restrict__ wp, const float* __restrict__ ccW,
                                              const float* __restrict__ ccb, float* __restrict__ pc) {
    __shared__ float tmp[128], af[128], pooled[128];
    int b = blockIdx.x, t = threadIdx.x;
    const float* qrow = qf + ((size_t)(b * 128 + t) << 7);
    float s = 0.f;
    for (int d = 0; d < 128; ++d) s += qrow[d] * wp[d];
    s += (1.f - qmask[b * 128 + t]) * (-1e30f);
    tmp[t] = s;
    __syncthreads();
    for (int off = 64; off >= 1; off >>= 1) {
        if (t < off) tmp[t] = fmaxf(tmp[t], tmp[t + off]);
        __syncthreads();
    }
    float m = tmp[0];
    __syncthreads();
    float e = __expf(s - m);
    tmp[t] = e;
    __syncthreads();
    for (int off = 64; off >= 1; off >>= 1) {
        if (t < off) tmp[t] += tmp[t + off];
        __syncthreads();
    }
    af[t] = e / tmp[0];
    __syncthreads();
    float p = 0.f;
    for (int q = 0; q < 128; ++q) p += qf[((size_t)(b * 128 + q) << 7) + t] * af[q];
    pooled[t] = p;
    __syncthreads();
    float acc = ccb[t];
    for (int d = 0; d < 128; ++d) acc += pooled[d] * ccW[t * 256 + 128 + d];
    pc[b * 128 + t] = acc;
}

// T^T with full-K per block, sync-free main loop, no atomics. grid (8 qtiles, 64 b).
// Ttf[b,d,q] = (1/colsum[b,q]) * sum_c exp(score[c,q]+cv'[c]) * vf[c,d], written as bf16 B-frags.
__global__ __launch_bounds__(256) void k_Tacc(const short* __restrict__ vfA, const short* __restrict__ vfT,
                                              const short* __restrict__ qfBW, const float* __restrict__ cvp,
                                              short* __restrict__ Ttf) {
    __shared__ short Al[16 * 136];  // e_t A-layout [q 16][c 128], wave-private columns
    __shared__ float Red[4][16][130];
    __shared__ float csred[4][16];
    __shared__ float csinv[16];
    int tid = threadIdx.x, w = tid >> 6, lane = tid & 63, ln = lane & 15, quad = lane >> 4;
    int b = blockIdx.y, qt = blockIdx.x;
    short8 bq[4];
#pragma unroll
    for (int ks = 0; ks < 4; ++ks) bq[ks] = *(const short8*)(qfBW + (((size_t)(b * 8 + qt) * 4 + ks) << 9) + lane * 8);
    float4v acc[8];
#pragma unroll
    for (int dt = 0; dt < 8; ++dt) acc[dt] = (float4v){0.f, 0.f, 0.f, 0.f};
    float colacc = 0.f;
    for (int it = 0; it < 16; ++it) {
        int cbase = it * 128 + w * 32;
        int ct = b * 128 + (cbase >> 4);
        // score: D[m=c 32][n=q 16] per wave
        float4v ds[2];
        ds[0] = (float4v){0.f, 0.f, 0.f, 0.f};
        ds[1] = (float4v){0.f, 0.f, 0.f, 0.f};
#pragma unroll
        for (int ks = 0; ks < 4; ++ks) {
#pragma unroll
            for (int mt = 0; mt < 2; ++mt) {
                short8 a = *(const short8*)(vfA + (((size_t)(ct + mt) * 4 + ks) << 9) + lane * 8);
                ds[mt] = MFMA16(a, bq[ks], ds[mt]);
            }
        }
        // e_t -> Al (A layout: row q=ln, col c), colsum partial
#pragma unroll
        for (int mt = 0; mt < 2; ++mt) {
            float4v cv = *(const float4v*)(cvp + b * 2048 + cbase + mt * 16 + quad * 4);
            short4v ev;
#pragma unroll
            for (int r = 0; r < 4; ++r) {
                float e = __expf(ds[mt][r] + cv[r]);
                colacc += e;
                ev[r] = f2b(e);
            }
            *(short4v*)(Al + ln * 136 + w * 32 + mt * 16 + quad * 4) = ev;
        }
        // T-GEMM: acc[dt] += e_t[q][c(32)] x vfT[d][c]
        short8 a = *(const short8*)(Al + ln * 136 + w * 32 + quad * 8);
#pragma unroll
        for (int dt = 0; dt < 8; ++dt) {
            short8 bb = *(const short8*)(vfT + (((size_t)(b * 8 + dt) * 64 + it * 4 + w) << 9) + lane * 8);
            acc[dt] = MFMA16(a, bb, acc[dt]);
        }
    }
    // cross-wave reduce
#pragma unroll
    for (int dt = 0; dt < 8; ++dt)
#pragma unroll
        for (int r = 0; r < 4; ++r) Red[w][quad * 4 + r][dt * 16 + ln] = acc[dt][r];
    float p = colacc;
    p += __shfl_xor(p, 16, 64);
    p += __shfl_xor(p, 32, 64);
    if (lane < 16) csred[w][lane] = p;
    __syncthreads();
    if (tid < 16) csinv[tid] = 1.f / (csred[0][tid] + csred[1][tid] + csred[2][tid] + csred[3][tid]);
    __syncthreads();
    // normalize + write Ttf frags (half-frag per block)
    {
        int qg = tid >> 7, d = tid & 127;
        int dt = d >> 4, ks = qt >> 1;
        int lane_o = ((qt & 1) * 2 + qg) * 16 + (d & 15);
        short8 v;
#pragma unroll
        for (int j = 0; j < 8; ++j) {
            int q = qg * 8 + j;
            float s = Red[0][q][d] + Red[1][q][d] + Red[2][q][d] + Red[3][q][d];
            v[j] = f2b(s * csinv[q]);
        }
        *(short8*)(Ttf + (((size_t)(b * 8 + dt) * 4 + ks) << 9) + lane_o * 8) = v;
    }
}

// Mega kernel, all frag-packed operands. grid (C/64, B), 256 thr.
__global__ __launch_bounds__(256) void k_out(const short* __restrict__ vfA, const short* __restrict__ qfBW,
                                             const short* __restrict__ qTf, const short* __restrict__ Ttf,
                                             const float* __restrict__ qvp, const short* __restrict__ cqaWp,
                                             const float* __restrict__ cqab, const short* __restrict__ ccWp,
                                             const float* __restrict__ pc, float* __restrict__ out) {
    __shared__ short Sl[64 * 136];   // score_, later feats
    __shared__ short C2l[64 * 136];  // c2q
    __shared__ short Q2l[64 * 136];  // q2c
    int tid = threadIdx.x, w = tid >> 6, lane = tid & 63, ln = lane & 15, quad = lane >> 4;
    int b = blockIdx.y, c0 = blockIdx.x * 64 + w * 16;
    int tt = b * 128 + (c0 >> 4);
    // ---- score tile: 16c x 128q (A = raw v, B = w∘q) ----
    short8 av[4];
    float4v sc[8];
#pragma unroll
    for (int qt = 0; qt < 8; ++qt) sc[qt] = (float4v){0.f, 0.f, 0.f, 0.f};
#pragma unroll
    for (int ks = 0; ks < 4; ++ks) {
        av[ks] = *(const short8*)(vfA + (((size_t)tt * 4 + ks) << 9) + lane * 8);
#pragma unroll
        for (int qt = 0; qt < 8; ++qt) {
            short8 bq = *(const short8*)(qfBW + (((size_t)(b * 8 + qt) * 4 + ks) << 9) + lane * 8);
            sc[qt] = MFMA16(av[ks], bq, sc[qt]);
        }
    }
    float qvl[8];
#pragma unroll
    for (int qt = 0; qt < 8; ++qt) qvl[qt] = qvp[b * 128 + qt * 16 + ln];
    // ---- row softmax over q ----
#pragma unroll
    for (int r = 0; r < 4; ++r) {
        float x[8], m = -3.4e38f;
#pragma unroll
        for (int qt = 0; qt < 8; ++qt) {
            x[qt] = sc[qt][r] + qvl[qt];
            m = fmaxf(m, x[qt]);
        }
#pragma unroll
        for (int off = 1; off < 16; off <<= 1) m = fmaxf(m, __shfl_xor(m, off, 64));
        float e[8], sm = 0.f;
#pragma unroll
        for (int qt = 0; qt < 8; ++qt) {
            e[qt] = __expf(x[qt] - m);
            sm += e[qt];
        }
#pragma unroll
        for (int off = 1; off < 16; off <<= 1) sm += __shfl_xor(sm, off, 64);
        float inv = 1.f / sm;
        int row = w * 16 + quad * 4 + r;
#pragma unroll
        for (int qt = 0; qt < 8; ++qt) Sl[row * 136 + qt * 16 + ln] = f2b(e[qt] * inv);
    }
    __syncthreads();
    // ---- c2q = score_ @ qf ; q2c = score_ @ T ----
    float4v a2q[8], aq2[8];
#pragma unroll
    for (int dt = 0; dt < 8; ++dt) {
        a2q[dt] = (float4v){0.f, 0.f, 0.f, 0.f};
        aq2[dt] = (float4v){0.f, 0.f, 0.f, 0.f};
    }
#pragma unroll
    for (int ks = 0; ks < 4; ++ks) {
        short8 a = *(const short8*)(Sl + (w * 16 + ln) * 136 + ks * 32 + quad * 8);
#pragma unroll
        for (int dt = 0; dt < 8; ++dt) {
            short8 b1 = *(const short8*)(qTf + (((size_t)(b * 8 + dt) * 4 + ks) << 9) + lane * 8);
            a2q[dt] = MFMA16(a, b1, a2q[dt]);
            short8 b2 = *(const short8*)(Ttf + (((size_t)(b * 8 + dt) * 4 + ks) << 9) + lane * 8);
            aq2[dt] = MFMA16(a, b2, aq2[dt]);
        }
    }
    __syncthreads();
#pragma unroll
    for (int dt = 0; dt < 8; ++dt)
#pragma unroll
        for (int r = 0; r < 4; ++r) {
            int row = w * 16 + quad * 4 + r;
            C2l[row * 136 + dt * 16 + ln] = f2b(a2q[dt][r]);
            Q2l[row * 136 + dt * 16 + ln] = f2b(aq2[dt][r]);
        }
    __syncthreads();
    // ---- feats = [v, c2q, v*c2q, v*q2c] @ cqa_W.T + cqa_b ----
    float4v accF[8];
#pragma unroll
    for (int nt = 0; nt < 8; ++nt) accF[nt] = (float4v){0.f, 0.f, 0.f, 0.f};
#pragma unroll
    for (int ks = 0; ks < 4; ++ks) {
        int co = ks * 32 + quad * 8;
        short8 ac = *(const short8*)(C2l + (w * 16 + ln) * 136 + co);
        short8 aq = *(const short8*)(Q2l + (w * 16 + ln) * 136 + co);
        short8 avc, avq;
#pragma unroll
        for (int j = 0; j < 8; ++j) {
            float fv = b2f(av[ks][j]);
            avc[j] = f2b(fv * b2f(ac[j]));
            avq[j] = f2b(fv * b2f(aq[j]));
        }
        short8 parts[4] = {av[ks], ac, avc, avq};
#pragma unroll
        for (int part = 0; part < 4; ++part) {
#pragma unroll
            for (int nt = 0; nt < 8; ++nt) {
                short8 bw = *(const short8*)(cqaWp + (((size_t)(nt * 4 + part) * 4 + ks) << 9) + lane * 8);
                accF[nt] = MFMA16(parts[part], bw, accF[nt]);
            }
        }
    }
    __syncthreads();  // done reading Sl as score_
#pragma unroll
    for (int nt = 0; nt < 8; ++nt) {
        int j = nt * 16 + ln;
        float bj = cqab[j];
#pragma unroll
        for (int r = 0; r < 4; ++r) Sl[(w * 16 + quad * 4 + r) * 136 + j] = f2b(accF[nt][r] + bj);
    }
    __syncthreads();
    // ---- out = relu(feats @ ccW[:, :128].T + pc) ----
    float4v accO[8];
#pragma unroll
    for (int ot = 0; ot < 8; ++ot) accO[ot] = (float4v){0.f, 0.f, 0.f, 0.f};
#pragma unroll
    for (int ks = 0; ks < 4; ++ks) {
        short8 a2 = *(const short8*)(Sl + (w * 16 + ln) * 136 + ks * 32 + quad * 8);
#pragma unroll
        for (int ot = 0; ot < 8; ++ot) {
            short8 bw = *(const short8*)(ccWp + (((size_t)(ot * 4 + ks)) << 9) + lane * 8);
            accO[ot] = MFMA16(a2, bw, accO[ot]);
        }
    }
#pragma unroll
    for (int ot = 0; ot < 8; ++ot) {
        int o = ot * 16 + ln;
        float pco = pc[b * 128 + o];
#pragma unroll
        for (int r = 0; r < 4; ++r) {
            int c = c0 + quad * 4 + r;
            out[((size_t)(b * 2048 + c) << 7) + o] = fmaxf(accO[ot][r] + pco, 0.f);
        }
    }
}

extern "C" void kernel_launch(void* const* d_in, const int* in_sizes, int n_in, void* d_out, int out_size, void* d_ws,
                              size_t ws_size, hipStream_t stream) {
    const float* vf = (const float*)d_in[0];
    const float* qf = (const float*)d_in[1];
    const float* vmask = (const float*)d_in[2];
    const float* qmask = (const float*)d_in[3];
    const float* w4C = (const float*)d_in[4];
    const float* w4Q = (const float*)d_in[5];
    const float* w4mlu = (const float*)d_in[6];
    const float* cqaW = (const float*)d_in[7];
    const float* cqab = (const float*)d_in[8];
    const float* wp = (const float*)d_in[9];
    const float* ccW = (const float*)d_in[10];
    const float* ccb = (const float*)d_in[11];
    float* out = (float*)d_out;
    char* ws = (char*)d_ws;

    // workspace layout (~74 MB)
    size_t o = 0;
    short* vfA = (short*)(ws + o); o += 64ull * 2048 * 128 * 2;   // 33.5 MB row-frags of vf
    short* vfT = (short*)(ws + o); o += 64ull * 2048 * 128 * 2;   // 33.5 MB transposed B-frags of vf
    short* qfBW = (short*)(ws + o); o += 64ull * 128 * 128 * 2;   // 2 MB row-frags of w4mlu∘qf
    short* qTf = (short*)(ws + o); o += 64ull * 128 * 128 * 2;    // 2 MB transposed B-frags of qf
    short* Ttf = (short*)(ws + o); o += 64ull * 128 * 128 * 2;    // 2 MB T^T B-frags
    short* cqaWp = (short*)(ws + o); o += 128ull * 512 * 2;       // 128 KB
    short* ccWp = (short*)(ws + o); o += 128ull * 128 * 2;        // 32 KB
    float* cvp = (float*)(ws + o); o += 64ull * 2048 * 4;         // 512 KB
    float* qvp = (float*)(ws + o); o += 64ull * 128 * 4;
    float* pc = (float*)(ws + o); o += 64ull * 128 * 4;

    k_packrows_dot<<<8192, 256, 0, stream>>>(vf, w4C, vmask, vfA, cvp);
    k_packrowsW_dot<<<512, 256, 0, stream>>>(qf, w4mlu, w4Q, qmask, qfBW, qvp);
    k_packTv<<<dim3(64, 64), 256, 0, stream>>>(vf, vfT, 64);
    k_packTv<<<dim3(4, 64), 256, 0, stream>>>(qf, qTf, 4);
    k_packW<<<32, 256, 0, stream>>>(cqaW, cqaWp);
    k_packWc<<<8, 256, 0, stream>>>(ccW, ccWp);
    k_pool<<<64, 128, 0, stream>>>(qf, qmask, wp, ccW, ccb, pc);
    k_Tacc<<<dim3(8, 64), 256, 0, stream>>>(vfA, vfT, qfBW, cvp, Ttf);
    k_out<<<dim3(32, 64), 256, 0, stream>>>(vfA, qfBW, qTf, Ttf, qvp, cqaWp, cqab, ccWp, pc, out);
}

// Round 6
// 388.464 us; speedup vs baseline: 2.1310x; 1.0754x over previous
//
#include <hip/hip_runtime.h>
#include <stdint.h>

#define DI __device__ __forceinline__

typedef __attribute__((ext_vector_type(8))) short short8;
typedef __attribute__((ext_vector_type(4))) short short4v;
typedef __attribute__((ext_vector_type(4))) float float4v;

#define MFMA16(a, b, c) __builtin_amdgcn_mfma_f32_16x16x32_bf16((a), (b), (c), 0, 0, 0)

DI float b2f(short s) {
    uint32_t u = ((uint32_t)(uint16_t)s) << 16;
    float f;
    __builtin_memcpy(&f, &u, 4);
    return f;
}
DI short f2b(float f) {
    uint32_t x;
    __builtin_memcpy(&x, &f, 4);
    x += 0x7fffu + ((x >> 16) & 1u);
    return (short)(uint16_t)(x >> 16);
}

// B=64, C=2048, Q=128, D=128. Frag layout: frag_id*512 + lane*8 (+j), bf16.
// A/B frag mapping: row = tile*16 + (lane&15), col(k) = ks*32 + (lane>>4)*8 + j.

// Pack row-major fp32 [tiles*16 x 128] -> frag tiles, fused row-dot (cv/qv).
__global__ __launch_bounds__(256) void k_packrows_dot(const float* __restrict__ src, const float* __restrict__ wv,
                                                      const float* __restrict__ mask, short* __restrict__ dst,
                                                      float* __restrict__ dotout) {
    int tile = blockIdx.x, t = threadIdx.x;
    int r = t >> 4, c16 = t & 15;
    int ks = c16 >> 2, quad = c16 & 3;
    const float* p = src + ((size_t)(tile * 16 + r) << 7) + c16 * 8;
    float4v a = *(const float4v*)p, b = *(const float4v*)(p + 4);
    float4v w0 = *(const float4v*)(wv + c16 * 8), w1 = *(const float4v*)(wv + c16 * 8 + 4);
    short8 v;
    float s = 0.f;
#pragma unroll
    for (int j = 0; j < 4; ++j) {
        v[j] = f2b(a[j]);
        v[4 + j] = f2b(b[j]);
        s += a[j] * w0[j] + b[j] * w1[j];
    }
    *(short8*)(dst + ((size_t)(tile * 4 + ks) << 9) + (quad * 16 + r) * 8) = v;
#pragma unroll
    for (int off = 1; off < 16; off <<= 1) s += __shfl_xor(s, off, 64);
    if (c16 == 0) {
        int gr = tile * 16 + r;
        dotout[gr] = s + (1.f - mask[gr]) * (-1e30f);
    }
}

// Same but multiplies packed values by w4mlu (score B operand: w∘q); dot uses raw values.
__global__ __launch_bounds__(256) void k_packrowsW_dot(const float* __restrict__ src, const float* __restrict__ wm,
                                                       const float* __restrict__ wv, const float* __restrict__ mask,
                                                       short* __restrict__ dst, float* __restrict__ dotout) {
    int tile = blockIdx.x, t = threadIdx.x;
    int r = t >> 4, c16 = t & 15;
    int ks = c16 >> 2, quad = c16 & 3;
    const float* p = src + ((size_t)(tile * 16 + r) << 7) + c16 * 8;
    float4v a = *(const float4v*)p, b = *(const float4v*)(p + 4);
    float4v w0 = *(const float4v*)(wv + c16 * 8), w1 = *(const float4v*)(wv + c16 * 8 + 4);
    float4v m0 = *(const float4v*)(wm + c16 * 8), m1 = *(const float4v*)(wm + c16 * 8 + 4);
    short8 v;
    float s = 0.f;
#pragma unroll
    for (int j = 0; j < 4; ++j) {
        v[j] = f2b(a[j] * m0[j]);
        v[4 + j] = f2b(b[j] * m1[j]);
        s += a[j] * w0[j] + b[j] * w1[j];
    }
    *(short8*)(dst + ((size_t)(tile * 4 + ks) << 9) + (quad * 16 + r) * 8) = v;
#pragma unroll
    for (int off = 1; off < 16; off <<= 1) s += __shfl_xor(s, off, 64);
    if (c16 == 0) {
        int gr = tile * 16 + r;
        dotout[gr] = s + (1.f - mask[gr]) * (-1e30f);
    }
}

// Transpose-pack src [b][rows=nkc*32][128] fp32 -> B-frags over (n=col d, k=row).
__global__ __launch_bounds__(256) void k_packTv(const float* __restrict__ src, short* __restrict__ dst, int nkc) {
    __shared__ float St[32 * 133];
    int t = threadIdx.x, kc = blockIdx.x, b = blockIdx.y;
    int rl = t >> 3, dseg = (t & 7) * 16;
    const float* p = src + ((size_t)((b * nkc + kc) * 32 + rl) << 7) + dseg;
#pragma unroll
    for (int g = 0; g < 4; ++g) {
        float4v v = *(const float4v*)(p + g * 4);
#pragma unroll
        for (int j = 0; j < 4; ++j) St[rl * 133 + dseg + g * 4 + j] = v[j];
    }
    __syncthreads();
#pragma unroll
    for (int i = 0; i < 2; ++i) {
        int dt = (t >> 6) + i * 4;
        int lane = t & 63, ln = lane & 15, quad = lane >> 4;
        int d = dt * 16 + ln;
        short8 v;
#pragma unroll
        for (int j = 0; j < 8; ++j) v[j] = f2b(St[(quad * 8 + j) * 133 + d]);
        *(short8*)(dst + (((size_t)(b * 8 + dt) * nkc + kc) << 9) + lane * 8) = v;
    }
}

// Pack cqa_W [128][512] fp32 -> frags ((nt*4+part)*4+ks).
__global__ __launch_bounds__(256) void k_packW(const float* __restrict__ wsrc, short* __restrict__ dst) {
    int idx = blockIdx.x * 256 + threadIdx.x;  // 8192
    int lane = idx & 63, ks = (idx >> 6) & 3, part = (idx >> 8) & 3, nt = idx >> 10;
    const float* p = wsrc + (size_t)(nt * 16 + (lane & 15)) * 512 + part * 128 + ks * 32 + (lane >> 4) * 8;
    float4v a = *(const float4v*)p, b = *(const float4v*)(p + 4);
    short8 v;
#pragma unroll
    for (int j = 0; j < 4; ++j) {
        v[j] = f2b(a[j]);
        v[4 + j] = f2b(b[j]);
    }
    *(short8*)(dst + (size_t)idx * 8) = v;
}

// Pack cc_W[:, :128] ([128][256] fp32) -> frags (ot*4+ks).
__global__ __launch_bounds__(256) void k_packWc(const float* __restrict__ wsrc, short* __restrict__ dst) {
    int idx = blockIdx.x * 256 + threadIdx.x;  // 2048
    int lane = idx & 63, ks = (idx >> 6) & 3, ot = idx >> 8;
    const float* p = wsrc + (size_t)(ot * 16 + (lane & 15)) * 256 + ks * 32 + (lane >> 4) * 8;
    float4v a = *(const float4v*)p, b = *(const float4v*)(p + 4);
    short8 v;
#pragma unroll
    for (int j = 0; j < 4; ++j) {
        v[j] = f2b(a[j]);
        v[4 + j] = f2b(b[j]);
    }
    *(short8*)(dst + (size_t)idx * 8) = v;
}

// alpha = softmax_q(qf@wp + mask); pooled; pc[b,o] = cc_b[o] + pooled·cc_W[o,128:]
__global__ __launch_bounds__(128) void k_pool(const float* __restrict__ qf, const float* __restrict__ qmask,
                                              const float* __restrict__ wp, const float* __restrict__ ccW,
                                              const float* __restrict__ ccb, float* __restrict__ pc) {
    __shared__ float tmp[128], af[128], pooled[128];
    int b = blockIdx.x, t = threadIdx.x;
    const float* qrow = qf + ((size_t)(b * 128 + t) << 7);
    float s = 0.f;
    for (int d = 0; d < 128; ++d) s += qrow[d] * wp[d];
    s += (1.f - qmask[b * 128 + t]) * (-1e30f);
    tmp[t] = s;
    __syncthreads();
    for (int off = 64; off >= 1; off >>= 1) {
        if (t < off) tmp[t] = fmaxf(tmp[t], tmp[t + off]);
        __syncthreads();
    }
    float m = tmp[0];
    __syncthreads();
    float e = __expf(s - m);
    tmp[t] = e;
    __syncthreads();
    for (int off = 64; off >= 1; off >>= 1) {
        if (t < off) tmp[t] += tmp[t + off];
        __syncthreads();
    }
    af[t] = e / tmp[0];
    __syncthreads();
    float p = 0.f;
    for (int q = 0; q < 128; ++q) p += qf[((size_t)(b * 128 + q) << 7) + t] * af[q];
    pooled[t] = p;
    __syncthreads();
    float acc = ccb[t];
    for (int d = 0; d < 128; ++d) acc += pooled[d] * ccW[t * 256 + 128 + d];
    pc[b * 128 + t] = acc;
}

// T^T partial accumulation over a C-half; deterministic fp32 partials, no atomics.
// grid (8 qtiles, 64 b, 2 s). Pg[(s*64+b)*8+qt][16 q][128 d]; Csg[(s*64+b)*128+q].
__global__ __launch_bounds__(256) void k_Tacc(const short* __restrict__ vfA, const short* __restrict__ vfT,
                                              const short* __restrict__ qfBW, const float* __restrict__ cvp,
                                              float* __restrict__ Pg, float* __restrict__ Csg) {
    __shared__ short Al[16 * 136];  // e_t A-layout [q 16][c 128], wave-private columns
    __shared__ float Red[4][16][130];
    __shared__ float csred[4][16];
    int tid = threadIdx.x, w = tid >> 6, lane = tid & 63, ln = lane & 15, quad = lane >> 4;
    int b = blockIdx.y, qt = blockIdx.x, s = blockIdx.z;
    short8 bq[4];
#pragma unroll
    for (int ks = 0; ks < 4; ++ks) bq[ks] = *(const short8*)(qfBW + (((size_t)(b * 8 + qt) * 4 + ks) << 9) + lane * 8);
    float4v acc[8];
#pragma unroll
    for (int dt = 0; dt < 8; ++dt) acc[dt] = (float4v){0.f, 0.f, 0.f, 0.f};
    float colacc = 0.f;
    for (int it = 0; it < 8; ++it) {
        int cbase = s * 1024 + it * 128 + w * 32;
        int ct = b * 128 + (cbase >> 4);
        float4v ds[2];
        ds[0] = (float4v){0.f, 0.f, 0.f, 0.f};
        ds[1] = (float4v){0.f, 0.f, 0.f, 0.f};
#pragma unroll
        for (int ks = 0; ks < 4; ++ks) {
#pragma unroll
            for (int mt = 0; mt < 2; ++mt) {
                short8 a = *(const short8*)(vfA + (((size_t)(ct + mt) * 4 + ks) << 9) + lane * 8);
                ds[mt] = MFMA16(a, bq[ks], ds[mt]);
            }
        }
#pragma unroll
        for (int mt = 0; mt < 2; ++mt) {
            float4v cv = *(const float4v*)(cvp + b * 2048 + cbase + mt * 16 + quad * 4);
            short4v ev;
#pragma unroll
            for (int r = 0; r < 4; ++r) {
                float e = __expf(ds[mt][r] + cv[r]);
                colacc += e;
                ev[r] = f2b(e);
            }
            *(short4v*)(Al + ln * 136 + w * 32 + mt * 16 + quad * 4) = ev;
        }
        short8 a = *(const short8*)(Al + ln * 136 + w * 32 + quad * 8);
#pragma unroll
        for (int dt = 0; dt < 8; ++dt) {
            short8 bb = *(const short8*)(vfT + (((size_t)(b * 8 + dt) * 64 + s * 32 + it * 4 + w) << 9) + lane * 8);
            acc[dt] = MFMA16(a, bb, acc[dt]);
        }
    }
    // cross-wave reduce -> global partials
#pragma unroll
    for (int dt = 0; dt < 8; ++dt)
#pragma unroll
        for (int r = 0; r < 4; ++r) Red[w][quad * 4 + r][dt * 16 + ln] = acc[dt][r];
    float p = colacc;
    p += __shfl_xor(p, 16, 64);
    p += __shfl_xor(p, 32, 64);
    if (lane < 16) csred[w][lane] = p;
    __syncthreads();
    if (tid < 16)
        Csg[((size_t)(s * 64 + b)) * 128 + qt * 16 + tid] =
            csred[0][tid] + csred[1][tid] + csred[2][tid] + csred[3][tid];
    {
        int q = tid >> 4, db = (tid & 15) * 8;
        float4v s0, s1;
#pragma unroll
        for (int j = 0; j < 4; ++j) {
            s0[j] = Red[0][q][db + j] + Red[1][q][db + j] + Red[2][q][db + j] + Red[3][q][db + j];
            s1[j] = Red[0][q][db + 4 + j] + Red[1][q][db + 4 + j] + Red[2][q][db + 4 + j] + Red[3][q][db + 4 + j];
        }
        size_t pb = (((size_t)(s * 64 + b)) * 8 + qt) * 2048 + q * 128 + db;
        *(float4v*)(Pg + pb) = s0;
        *(float4v*)(Pg + pb + 4) = s1;
    }
}

// Combine 2 partials + colsum -> Ttf bf16 B-frags.
__global__ __launch_bounds__(256) void k_Tcomb(const float* __restrict__ Pg, const float* __restrict__ Csg,
                                               short* __restrict__ Ttf) {
    int idx = blockIdx.x * 256 + threadIdx.x;  // 131072
    int lane = idx & 63, dt = (idx >> 8) & 7, b = idx >> 11;
    int d = dt * 16 + (lane & 15), q0 = ((idx >> 6) & 3) * 32 + (lane >> 4) * 8;
    short8 v;
#pragma unroll
    for (int j = 0; j < 8; ++j) {
        int q = q0 + j;
        size_t o0 = ((size_t)(b * 8) + (q >> 4)) * 2048 + (q & 15) * 128 + d;
        size_t o1 = ((size_t)((64 + b) * 8) + (q >> 4)) * 2048 + (q & 15) * 128 + d;
        float pv = Pg[o0] + Pg[o1];
        float cs = Csg[b * 128 + q] + Csg[(64 + b) * 128 + q];
        v[j] = f2b(pv / cs);
    }
    *(short8*)(Ttf + (size_t)idx * 8) = v;
}

// Mega kernel, zero barriers (all LDS wave-private). grid (C/64, B), 256 thr.
__global__ __launch_bounds__(256, 4) void k_out(const short* __restrict__ vfA, const short* __restrict__ qfBW,
                                                const short* __restrict__ qTf, const short* __restrict__ Ttf,
                                                const float* __restrict__ qvp, const short* __restrict__ cqaWp,
                                                const float* __restrict__ cqab, const short* __restrict__ ccWp,
                                                const float* __restrict__ pc, float* __restrict__ out) {
    __shared__ short Sl[64 * 136];  // score_, later feats (wave-private rows)
    __shared__ short Xl[64 * 136];  // c2q, later q2c (wave-private rows)
    int tid = threadIdx.x, w = tid >> 6, lane = tid & 63, ln = lane & 15, quad = lane >> 4;
    int b = blockIdx.y, c0 = blockIdx.x * 64 + w * 16;
    int tt = b * 128 + (c0 >> 4);
    int myrow = (w * 16 + ln) * 136;
    // ---- score tile: 16c x 128q (A = raw v, B = w∘q) ----
    short8 av[4];
    float4v sc[8];
#pragma unroll
    for (int qt = 0; qt < 8; ++qt) sc[qt] = (float4v){0.f, 0.f, 0.f, 0.f};
#pragma unroll
    for (int ks = 0; ks < 4; ++ks) {
        av[ks] = *(const short8*)(vfA + (((size_t)tt * 4 + ks) << 9) + lane * 8);
#pragma unroll
        for (int qt = 0; qt < 8; ++qt) {
            short8 bq = *(const short8*)(qfBW + (((size_t)(b * 8 + qt) * 4 + ks) << 9) + lane * 8);
            sc[qt] = MFMA16(av[ks], bq, sc[qt]);
        }
    }
    float qvl[8];
#pragma unroll
    for (int qt = 0; qt < 8; ++qt) qvl[qt] = qvp[b * 128 + qt * 16 + ln];
    // ---- row softmax over q ----
#pragma unroll
    for (int r = 0; r < 4; ++r) {
        float x[8], m = -3.4e38f;
#pragma unroll
        for (int qt = 0; qt < 8; ++qt) {
            x[qt] = sc[qt][r] + qvl[qt];
            m = fmaxf(m, x[qt]);
        }
#pragma unroll
        for (int off = 1; off < 16; off <<= 1) m = fmaxf(m, __shfl_xor(m, off, 64));
        float e[8], sm = 0.f;
#pragma unroll
        for (int qt = 0; qt < 8; ++qt) {
            e[qt] = __expf(x[qt] - m);
            sm += e[qt];
        }
#pragma unroll
        for (int off = 1; off < 16; off <<= 1) sm += __shfl_xor(sm, off, 64);
        float inv = 1.f / sm;
        int row = (w * 16 + quad * 4 + r) * 136;
#pragma unroll
        for (int qt = 0; qt < 8; ++qt) Sl[row + qt * 16 + ln] = f2b(e[qt] * inv);
    }
    // ---- c2q = score_ @ qf ----
    float4v a2q[8];
#pragma unroll
    for (int dt = 0; dt < 8; ++dt) a2q[dt] = (float4v){0.f, 0.f, 0.f, 0.f};
#pragma unroll
    for (int ks = 0; ks < 4; ++ks) {
        short8 a = *(const short8*)(Sl + myrow + ks * 32 + quad * 8);
#pragma unroll
        for (int dt = 0; dt < 8; ++dt) {
            short8 b1 = *(const short8*)(qTf + (((size_t)(b * 8 + dt) * 4 + ks) << 9) + lane * 8);
            a2q[dt] = MFMA16(a, b1, a2q[dt]);
        }
    }
#pragma unroll
    for (int dt = 0; dt < 8; ++dt)
#pragma unroll
        for (int r = 0; r < 4; ++r) Xl[(w * 16 + quad * 4 + r) * 136 + dt * 16 + ln] = f2b(a2q[dt][r]);
    // ---- cat GEMM parts 0 (v), 1 (c2q), 2 (v*c2q) ----
    float4v accF[8];
#pragma unroll
    for (int nt = 0; nt < 8; ++nt) accF[nt] = (float4v){0.f, 0.f, 0.f, 0.f};
#pragma unroll
    for (int ks = 0; ks < 4; ++ks) {
        short8 ac = *(const short8*)(Xl + myrow + ks * 32 + quad * 8);
        short8 avc;
#pragma unroll
        for (int j = 0; j < 8; ++j) avc[j] = f2b(b2f(av[ks][j]) * b2f(ac[j]));
#pragma unroll
        for (int nt = 0; nt < 8; ++nt) {
            accF[nt] = MFMA16(av[ks], *(const short8*)(cqaWp + (((size_t)(nt * 4 + 0) * 4 + ks) << 9) + lane * 8),
                              accF[nt]);
            accF[nt] =
                MFMA16(ac, *(const short8*)(cqaWp + (((size_t)(nt * 4 + 1) * 4 + ks) << 9) + lane * 8), accF[nt]);
            accF[nt] =
                MFMA16(avc, *(const short8*)(cqaWp + (((size_t)(nt * 4 + 2) * 4 + ks) << 9) + lane * 8), accF[nt]);
        }
    }
    // ---- q2c = score_ @ T ----
    float4v aq2[8];
#pragma unroll
    for (int dt = 0; dt < 8; ++dt) aq2[dt] = (float4v){0.f, 0.f, 0.f, 0.f};
#pragma unroll
    for (int ks = 0; ks < 4; ++ks) {
        short8 a = *(const short8*)(Sl + myrow + ks * 32 + quad * 8);
#pragma unroll
        for (int dt = 0; dt < 8; ++dt) {
            short8 b2 = *(const short8*)(Ttf + (((size_t)(b * 8 + dt) * 4 + ks) << 9) + lane * 8);
            aq2[dt] = MFMA16(a, b2, aq2[dt]);
        }
    }
#pragma unroll
    for (int dt = 0; dt < 8; ++dt)
#pragma unroll
        for (int r = 0; r < 4; ++r) Xl[(w * 16 + quad * 4 + r) * 136 + dt * 16 + ln] = f2b(aq2[dt][r]);
    // ---- cat GEMM part 3 (v*q2c) ----
#pragma unroll
    for (int ks = 0; ks < 4; ++ks) {
        short8 aq = *(const short8*)(Xl + myrow + ks * 32 + quad * 8);
        short8 avq;
#pragma unroll
        for (int j = 0; j < 8; ++j) avq[j] = f2b(b2f(av[ks][j]) * b2f(aq[j]));
#pragma unroll
        for (int nt = 0; nt < 8; ++nt)
            accF[nt] =
                MFMA16(avq, *(const short8*)(cqaWp + (((size_t)(nt * 4 + 3) * 4 + ks) << 9) + lane * 8), accF[nt]);
    }
    // ---- feats -> Sl (overwrite, wave-private) ----
#pragma unroll
    for (int nt = 0; nt < 8; ++nt) {
        int j = nt * 16 + ln;
        float bj = cqab[j];
#pragma unroll
        for (int r = 0; r < 4; ++r) Sl[(w * 16 + quad * 4 + r) * 136 + j] = f2b(accF[nt][r] + bj);
    }
    // ---- out = relu(feats @ ccW[:, :128].T + pc) ----
    float4v accO[8];
#pragma unroll
    for (int ot = 0; ot < 8; ++ot) accO[ot] = (float4v){0.f, 0.f, 0.f, 0.f};
#pragma unroll
    for (int ks = 0; ks < 4; ++ks) {
        short8 a2 = *(const short8*)(Sl + myrow + ks * 32 + quad * 8);
#pragma unroll
        for (int ot = 0; ot < 8; ++ot) {
            short8 bw = *(const short8*)(ccWp + (((size_t)(ot * 4 + ks)) << 9) + lane * 8);
            accO[ot] = MFMA16(a2, bw, accO[ot]);
        }
    }
#pragma unroll
    for (int ot = 0; ot < 8; ++ot) {
        int o = ot * 16 + ln;
        float pco = pc[b * 128 + o];
#pragma unroll
        for (int r = 0; r < 4; ++r) {
            int c = c0 + quad * 4 + r;
            out[((size_t)(b * 2048 + c) << 7) + o] = fmaxf(accO[ot][r] + pco, 0.f);
        }
    }
}

extern "C" void kernel_launch(void* const* d_in, const int* in_sizes, int n_in, void* d_out, int out_size, void* d_ws,
                              size_t ws_size, hipStream_t stream) {
    const float* vf = (const float*)d_in[0];
    const float* qf = (const float*)d_in[1];
    const float* vmask = (const float*)d_in[2];
    const float* qmask = (const float*)d_in[3];
    const float* w4C = (const float*)d_in[4];
    const float* w4Q = (const float*)d_in[5];
    const float* w4mlu = (const float*)d_in[6];
    const float* cqaW = (const float*)d_in[7];
    const float* cqab = (const float*)d_in[8];
    const float* wp = (const float*)d_in[9];
    const float* ccW = (const float*)d_in[10];
    const float* ccb = (const float*)d_in[11];
    float* out = (float*)d_out;
    char* ws = (char*)d_ws;

    // workspace layout (~83 MB)
    size_t o = 0;
    short* vfA = (short*)(ws + o); o += 64ull * 2048 * 128 * 2;   // 33.5 MB
    short* vfT = (short*)(ws + o); o += 64ull * 2048 * 128 * 2;   // 33.5 MB
    short* qfBW = (short*)(ws + o); o += 64ull * 128 * 128 * 2;   // 2 MB
    short* qTf = (short*)(ws + o); o += 64ull * 128 * 128 * 2;    // 2 MB
    short* Ttf = (short*)(ws + o); o += 64ull * 128 * 128 * 2;    // 2 MB
    short* cqaWp = (short*)(ws + o); o += 128ull * 512 * 2;       // 128 KB
    short* ccWp = (short*)(ws + o); o += 128ull * 128 * 2;        // 32 KB
    float* Pg = (float*)(ws + o); o += 2ull * 64 * 128 * 128 * 4; // 8.4 MB
    float* Csg = (float*)(ws + o); o += 2ull * 64 * 128 * 4;      // 64 KB
    float* cvp = (float*)(ws + o); o += 64ull * 2048 * 4;         // 512 KB
    float* qvp = (float*)(ws + o); o += 64ull * 128 * 4;
    float* pc = (float*)(ws + o); o += 64ull * 128 * 4;

    k_packrows_dot<<<8192, 256, 0, stream>>>(vf, w4C, vmask, vfA, cvp);
    k_packrowsW_dot<<<512, 256, 0, stream>>>(qf, w4mlu, w4Q, qmask, qfBW, qvp);
    k_packTv<<<dim3(64, 64), 256, 0, stream>>>(vf, vfT, 64);
    k_packTv<<<dim3(4, 64), 256, 0, stream>>>(qf, qTf, 4);
    k_packW<<<32, 256, 0, stream>>>(cqaW, cqaWp);
    k_packWc<<<8, 256, 0, stream>>>(ccW, ccWp);
    k_pool<<<64, 128, 0, stream>>>(qf, qmask, wp, ccW, ccb, pc);
    k_Tacc<<<dim3(8, 64, 2), 256, 0, stream>>>(vfA, vfT, qfBW, cvp, Pg, Csg);
    k_Tcomb<<<512, 256, 0, stream>>>(Pg, Csg, Ttf);
    k_out<<<dim3(32, 64), 256, 0, stream>>>(vfA, qfBW, qTf, Ttf, qvp, cqaWp, cqab, ccWp, pc, out);
}

// Round 7
// 280.440 us; speedup vs baseline: 2.9519x; 1.3852x over previous
//
#include <hip/hip_runtime.h>
#include <stdint.h>

#define DI __device__ __forceinline__

typedef __attribute__((ext_vector_type(8))) short short8;
typedef __attribute__((ext_vector_type(4))) short short4v;
typedef __attribute__((ext_vector_type(4))) float float4v;

#define MFMA16(a, b, c) __builtin_amdgcn_mfma_f32_16x16x32_bf16((a), (b), (c), 0, 0, 0)

DI float b2f(short s) {
    uint32_t u = ((uint32_t)(uint16_t)s) << 16;
    float f;
    __builtin_memcpy(&f, &u, 4);
    return f;
}
DI short f2b(float f) {
    uint32_t x;
    __builtin_memcpy(&x, &f, 4);
    x += 0x7fffu + ((x >> 16) & 1u);
    return (short)(uint16_t)(x >> 16);
}

// B=64, C=2048, Q=128, D=128. Frag layout: frag_id*512 + lane*8 (+j), bf16.
// A/B frag mapping: row = tile*16 + (lane&15), col(k) = ks*32 + (lane>>4)*8 + j.

// Fused pack of a 32-row slab of src [b][nkc*32][128]:
//  - A-frags (optionally pre-scaled by wm) -> dstA
//  - transposed B-frags (raw values)       -> dstT
//  - row-dot with wv + mask bias           -> dotout
__global__ __launch_bounds__(256) void k_packfuse(const float* __restrict__ src, const float* __restrict__ wm,
                                                  const float* __restrict__ wv, const float* __restrict__ mask,
                                                  short* __restrict__ dstA, short* __restrict__ dstT,
                                                  float* __restrict__ dotout, int nkc) {
    __shared__ float St[32 * 133];
    int t = threadIdx.x, kc = blockIdx.x, b = blockIdx.y;
    int rl = t >> 3, sub = t & 7, dseg = sub * 16;
    int grow = (b * nkc + kc) * 32 + rl;
    const float* p = src + ((size_t)grow << 7) + dseg;
    float4v v[4];
#pragma unroll
    for (int g = 0; g < 4; ++g) v[g] = *(const float4v*)(p + g * 4);
    // row-dot (raw values)
    float s = 0.f;
#pragma unroll
    for (int g = 0; g < 4; ++g) {
        float4v wg = *(const float4v*)(wv + dseg + g * 4);
#pragma unroll
        for (int j = 0; j < 4; ++j) s += v[g][j] * wg[j];
    }
#pragma unroll
    for (int off = 1; off < 8; off <<= 1) s += __shfl_xor(s, off, 64);
    if (sub == 0) dotout[grow] = s + (1.f - mask[grow]) * (-1e30f);
    // stage raw to LDS for transpose
#pragma unroll
    for (int g = 0; g < 4; ++g)
#pragma unroll
        for (int j = 0; j < 4; ++j) St[rl * 133 + dseg + g * 4 + j] = v[g][j];
    // A-frags (scaled by wm if given)
#pragma unroll
    for (int h = 0; h < 2; ++h) {
        int c16 = sub * 2 + h;
        int ks = c16 >> 2, quad = c16 & 3;
        float4v m0 = wm ? *(const float4v*)(wm + c16 * 8) : (float4v){1.f, 1.f, 1.f, 1.f};
        float4v m1 = wm ? *(const float4v*)(wm + c16 * 8 + 4) : (float4v){1.f, 1.f, 1.f, 1.f};
        short8 o;
#pragma unroll
        for (int j = 0; j < 4; ++j) {
            o[j] = f2b(v[h * 2][j] * m0[j]);
            o[4 + j] = f2b(v[h * 2 + 1][j] * m1[j]);
        }
        int tile = b * (nkc * 2) + kc * 2 + (rl >> 4);
        *(short8*)(dstA + ((size_t)(tile * 4 + ks) << 9) + (quad * 16 + (rl & 15)) * 8) = o;
    }
    __syncthreads();
    // transposed B-frags
#pragma unroll
    for (int i = 0; i < 2; ++i) {
        int dt = (t >> 6) + i * 4;
        int lane = t & 63, ln = lane & 15, quad = lane >> 4;
        int d = dt * 16 + ln;
        short8 o;
#pragma unroll
        for (int j = 0; j < 8; ++j) o[j] = f2b(St[(quad * 8 + j) * 133 + d]);
        *(short8*)(dstT + (((size_t)(b * 8 + dt) * nkc + kc) << 9) + lane * 8) = o;
    }
}

// Pack cqa_W [128][512] fp32 -> frags ((nt*4+part)*4+ks).
__global__ __launch_bounds__(256) void k_packW(const float* __restrict__ wsrc, short* __restrict__ dst) {
    int idx = blockIdx.x * 256 + threadIdx.x;  // 8192
    int lane = idx & 63, ks = (idx >> 6) & 3, part = (idx >> 8) & 3, nt = idx >> 10;
    const float* p = wsrc + (size_t)(nt * 16 + (lane & 15)) * 512 + part * 128 + ks * 32 + (lane >> 4) * 8;
    float4v a = *(const float4v*)p, b = *(const float4v*)(p + 4);
    short8 v;
#pragma unroll
    for (int j = 0; j < 4; ++j) {
        v[j] = f2b(a[j]);
        v[4 + j] = f2b(b[j]);
    }
    *(short8*)(dst + (size_t)idx * 8) = v;
}

// Pack cc_W[:, :128] ([128][256] fp32) -> frags (ot*4+ks).
__global__ __launch_bounds__(256) void k_packWc(const float* __restrict__ wsrc, short* __restrict__ dst) {
    int idx = blockIdx.x * 256 + threadIdx.x;  // 2048
    int lane = idx & 63, ks = (idx >> 6) & 3, ot = idx >> 8;
    const float* p = wsrc + (size_t)(ot * 16 + (lane & 15)) * 256 + ks * 32 + (lane >> 4) * 8;
    float4v a = *(const float4v*)p, b = *(const float4v*)(p + 4);
    short8 v;
#pragma unroll
    for (int j = 0; j < 4; ++j) {
        v[j] = f2b(a[j]);
        v[4 + j] = f2b(b[j]);
    }
    *(short8*)(dst + (size_t)idx * 8) = v;
}

// alpha = softmax_q(qf@wp + mask); pooled; pc[b,o] = cc_b[o] + pooled·cc_W[o,128:]
__global__ __launch_bounds__(128) void k_pool(const float* __restrict__ qf, const float* __restrict__ qmask,
                                              const float* __restrict__ wp, const float* __restrict__ ccW,
                                              const float* __restrict__ ccb, float* __restrict__ pc) {
    __shared__ float tmp[128], af[128], pooled[128];
    int b = blockIdx.x, t = threadIdx.x;
    const float* qrow = qf + ((size_t)(b * 128 + t) << 7);
    float s = 0.f;
    for (int d = 0; d < 128; ++d) s += qrow[d] * wp[d];
    s += (1.f - qmask[b * 128 + t]) * (-1e30f);
    tmp[t] = s;
    __syncthreads();
    for (int off = 64; off >= 1; off >>= 1) {
        if (t < off) tmp[t] = fmaxf(tmp[t], tmp[t + off]);
        __syncthreads();
    }
    float m = tmp[0];
    __syncthreads();
    float e = __expf(s - m);
    tmp[t] = e;
    __syncthreads();
    for (int off = 64; off >= 1; off >>= 1) {
        if (t < off) tmp[t] += tmp[t + off];
        __syncthreads();
    }
    af[t] = e / tmp[0];
    __syncthreads();
    float p = 0.f;
    for (int q = 0; q < 128; ++q) p += qf[((size_t)(b * 128 + q) << 7) + t] * af[q];
    pooled[t] = p;
    __syncthreads();
    float acc = ccb[t];
    for (int d = 0; d < 128; ++d) acc += pooled[d] * ccW[t * 256 + 128 + d];
    pc[b * 128 + t] = acc;
}

// T^T partials over a C-half; deterministic fp32, no atomics. grid flat 1024 (XCD-swizzled).
__global__ __launch_bounds__(256) void k_Tacc(const short* __restrict__ vfA, const short* __restrict__ vfT,
                                              const short* __restrict__ qfBW, const float* __restrict__ cvp,
                                              float* __restrict__ Pg, float* __restrict__ Csg) {
    __shared__ short Al[16 * 136];
    __shared__ float Red[4][16][130];
    __shared__ float csred[4][16];
    int tid = threadIdx.x, w = tid >> 6, lane = tid & 63, ln = lane & 15, quad = lane >> 4;
    // swizzle: keep all qt-blocks of one (b,s) on one XCD
    int id = blockIdx.x;
    int xcd = id & 7, k = id >> 3;
    int g = xcd * 16 + (k & 15);  // (b,s) group 0..127
    int qt = k >> 4;
    int b = g & 63, s = g >> 6;
    short8 bq[4];
#pragma unroll
    for (int ks = 0; ks < 4; ++ks) bq[ks] = *(const short8*)(qfBW + (((size_t)(b * 8 + qt) * 4 + ks) << 9) + lane * 8);
    float4v acc[8];
#pragma unroll
    for (int dt = 0; dt < 8; ++dt) acc[dt] = (float4v){0.f, 0.f, 0.f, 0.f};
    float colacc = 0.f;
    for (int it = 0; it < 8; ++it) {
        int cbase = s * 1024 + it * 128 + w * 32;
        int ct = b * 128 + (cbase >> 4);
        float4v ds[2];
        ds[0] = (float4v){0.f, 0.f, 0.f, 0.f};
        ds[1] = (float4v){0.f, 0.f, 0.f, 0.f};
#pragma unroll
        for (int ks = 0; ks < 4; ++ks) {
#pragma unroll
            for (int mt = 0; mt < 2; ++mt) {
                short8 a = *(const short8*)(vfA + (((size_t)(ct + mt) * 4 + ks) << 9) + lane * 8);
                ds[mt] = MFMA16(a, bq[ks], ds[mt]);
            }
        }
#pragma unroll
        for (int mt = 0; mt < 2; ++mt) {
            float4v cv = *(const float4v*)(cvp + b * 2048 + cbase + mt * 16 + quad * 4);
            short4v ev;
#pragma unroll
            for (int r = 0; r < 4; ++r) {
                float e = __expf(ds[mt][r] + cv[r]);
                colacc += e;
                ev[r] = f2b(e);
            }
            *(short4v*)(Al + ln * 136 + w * 32 + mt * 16 + quad * 4) = ev;
        }
        short8 a = *(const short8*)(Al + ln * 136 + w * 32 + quad * 8);
#pragma unroll
        for (int dt = 0; dt < 8; ++dt) {
            short8 bb = *(const short8*)(vfT + (((size_t)(b * 8 + dt) * 64 + s * 32 + it * 4 + w) << 9) + lane * 8);
            acc[dt] = MFMA16(a, bb, acc[dt]);
        }
    }
#pragma unroll
    for (int dt = 0; dt < 8; ++dt)
#pragma unroll
        for (int r = 0; r < 4; ++r) Red[w][quad * 4 + r][dt * 16 + ln] = acc[dt][r];
    float p = colacc;
    p += __shfl_xor(p, 16, 64);
    p += __shfl_xor(p, 32, 64);
    if (lane < 16) csred[w][lane] = p;
    __syncthreads();
    if (tid < 16)
        Csg[((size_t)(s * 64 + b)) * 128 + qt * 16 + tid] =
            csred[0][tid] + csred[1][tid] + csred[2][tid] + csred[3][tid];
    {
        int q = tid >> 4, db = (tid & 15) * 8;
        float4v s0, s1;
#pragma unroll
        for (int j = 0; j < 4; ++j) {
            s0[j] = Red[0][q][db + j] + Red[1][q][db + j] + Red[2][q][db + j] + Red[3][q][db + j];
            s1[j] = Red[0][q][db + 4 + j] + Red[1][q][db + 4 + j] + Red[2][q][db + 4 + j] + Red[3][q][db + 4 + j];
        }
        size_t pb = (((size_t)(s * 64 + b)) * 8 + qt) * 2048 + q * 128 + db;
        *(float4v*)(Pg + pb) = s0;
        *(float4v*)(Pg + pb + 4) = s1;
    }
}

// Combine 2 partials + colsum -> Ttf bf16 B-frags.
__global__ __launch_bounds__(256) void k_Tcomb(const float* __restrict__ Pg, const float* __restrict__ Csg,
                                               short* __restrict__ Ttf) {
    int idx = blockIdx.x * 256 + threadIdx.x;  // 131072
    int lane = idx & 63, dt = (idx >> 8) & 7, b = idx >> 11;
    int d = dt * 16 + (lane & 15), q0 = ((idx >> 6) & 3) * 32 + (lane >> 4) * 8;
    short8 v;
#pragma unroll
    for (int j = 0; j < 8; ++j) {
        int q = q0 + j;
        size_t o0 = ((size_t)(b * 8) + (q >> 4)) * 2048 + (q & 15) * 128 + d;
        size_t o1 = ((size_t)((64 + b) * 8) + (q >> 4)) * 2048 + (q & 15) * 128 + d;
        float pv = Pg[o0] + Pg[o1];
        float cs = Csg[b * 128 + q] + Csg[(64 + b) * 128 + q];
        v[j] = f2b(pv / cs);
    }
    *(short8*)(Ttf + (size_t)idx * 8) = v;
}

// Mega kernel, zero barriers, single accumulator family live at a time.
// grid flat 2048 (XCD-swizzled), 256 thr.
__global__ __launch_bounds__(256, 4) void k_out(const short* __restrict__ vfA, const short* __restrict__ qfBW,
                                                const short* __restrict__ qTf, const short* __restrict__ Ttf,
                                                const float* __restrict__ qvp, const short* __restrict__ cqaWp,
                                                const float* __restrict__ cqab, const short* __restrict__ ccWp,
                                                const float* __restrict__ pc, float* __restrict__ out) {
    __shared__ short Sl[64 * 136];  // score_ -> q2c -> feats (wave-private rows)
    __shared__ short Xl[64 * 136];  // c2q (wave-private rows)
    int tid = threadIdx.x, w = tid >> 6, lane = tid & 63, ln = lane & 15, quad = lane >> 4;
    // swizzle: all c-tiles of one b on one XCD
    int id = blockIdx.x;
    int xcd = id & 7, k = id >> 3;
    int b = xcd * 8 + (k & 7);
    int cx = k >> 3;
    int c0 = cx * 64 + w * 16;
    int tt = b * 128 + (c0 >> 4);
    int myrow = (w * 16 + ln) * 136;
    // ---- score tile: 16c x 128q (A = raw v, B = w∘q) ----
    short8 av[4];
    {
        float4v sc[8];
#pragma unroll
        for (int qt = 0; qt < 8; ++qt) sc[qt] = (float4v){0.f, 0.f, 0.f, 0.f};
#pragma unroll
        for (int ks = 0; ks < 4; ++ks) {
            av[ks] = *(const short8*)(vfA + (((size_t)tt * 4 + ks) << 9) + lane * 8);
#pragma unroll
            for (int qt = 0; qt < 8; ++qt) {
                short8 bq = *(const short8*)(qfBW + (((size_t)(b * 8 + qt) * 4 + ks) << 9) + lane * 8);
                sc[qt] = MFMA16(av[ks], bq, sc[qt]);
            }
        }
        float qvl[8];
#pragma unroll
        for (int qt = 0; qt < 8; ++qt) qvl[qt] = qvp[b * 128 + qt * 16 + ln];
        // ---- row softmax over q ----
#pragma unroll
        for (int r = 0; r < 4; ++r) {
            float x[8], m = -3.4e38f;
#pragma unroll
            for (int qt = 0; qt < 8; ++qt) {
                x[qt] = sc[qt][r] + qvl[qt];
                m = fmaxf(m, x[qt]);
            }
#pragma unroll
            for (int off = 1; off < 16; off <<= 1) m = fmaxf(m, __shfl_xor(m, off, 64));
            float e[8], sm = 0.f;
#pragma unroll
            for (int qt = 0; qt < 8; ++qt) {
                e[qt] = __expf(x[qt] - m);
                sm += e[qt];
            }
#pragma unroll
            for (int off = 1; off < 16; off <<= 1) sm += __shfl_xor(sm, off, 64);
            float inv = 1.f / sm;
            int row = (w * 16 + quad * 4 + r) * 136;
#pragma unroll
            for (int qt = 0; qt < 8; ++qt) Sl[row + qt * 16 + ln] = f2b(e[qt] * inv);
        }
    }
    // ---- c2q = score_ @ qf -> Xl ----
    {
        float4v a2q[8];
#pragma unroll
        for (int dt = 0; dt < 8; ++dt) a2q[dt] = (float4v){0.f, 0.f, 0.f, 0.f};
#pragma unroll
        for (int ks = 0; ks < 4; ++ks) {
            short8 a = *(const short8*)(Sl + myrow + ks * 32 + quad * 8);
#pragma unroll
            for (int dt = 0; dt < 8; ++dt) {
                short8 b1 = *(const short8*)(qTf + (((size_t)(b * 8 + dt) * 4 + ks) << 9) + lane * 8);
                a2q[dt] = MFMA16(a, b1, a2q[dt]);
            }
        }
#pragma unroll
        for (int dt = 0; dt < 8; ++dt)
#pragma unroll
            for (int r = 0; r < 4; ++r) Xl[(w * 16 + quad * 4 + r) * 136 + dt * 16 + ln] = f2b(a2q[dt][r]);
    }
    // ---- q2c = score_ @ T -> Sl (score_ dead afterwards; wave-private so safe) ----
    {
        float4v aq2[8];
#pragma unroll
        for (int dt = 0; dt < 8; ++dt) aq2[dt] = (float4v){0.f, 0.f, 0.f, 0.f};
#pragma unroll
        for (int ks = 0; ks < 4; ++ks) {
            short8 a = *(const short8*)(Sl + myrow + ks * 32 + quad * 8);
#pragma unroll
            for (int dt = 0; dt < 8; ++dt) {
                short8 b2 = *(const short8*)(Ttf + (((size_t)(b * 8 + dt) * 4 + ks) << 9) + lane * 8);
                aq2[dt] = MFMA16(a, b2, aq2[dt]);
            }
        }
#pragma unroll
        for (int dt = 0; dt < 8; ++dt)
#pragma unroll
            for (int r = 0; r < 4; ++r) Sl[(w * 16 + quad * 4 + r) * 136 + dt * 16 + ln] = f2b(aq2[dt][r]);
    }
    // ---- cat GEMM: [v, c2q, v*c2q, v*q2c] @ cqa_W.T ----
    float4v accF[8];
#pragma unroll
    for (int nt = 0; nt < 8; ++nt) accF[nt] = (float4v){0.f, 0.f, 0.f, 0.f};
#pragma unroll
    for (int ks = 0; ks < 4; ++ks) {
        short8 ac = *(const short8*)(Xl + myrow + ks * 32 + quad * 8);
        short8 aq = *(const short8*)(Sl + myrow + ks * 32 + quad * 8);
        short8 avc, avq;
#pragma unroll
        for (int j = 0; j < 8; ++j) {
            float fv = b2f(av[ks][j]);
            avc[j] = f2b(fv * b2f(ac[j]));
            avq[j] = f2b(fv * b2f(aq[j]));
        }
        short8 parts[4] = {av[ks], ac, avc, avq};
#pragma unroll
        for (int part = 0; part < 4; ++part) {
#pragma unroll
            for (int nt = 0; nt < 8; ++nt) {
                short8 bw = *(const short8*)(cqaWp + (((size_t)(nt * 4 + part) * 4 + ks) << 9) + lane * 8);
                accF[nt] = MFMA16(parts[part], bw, accF[nt]);
            }
        }
    }
    // ---- feats -> Sl (after all Sl-as-q2c reads; wave-private) ----
#pragma unroll
    for (int nt = 0; nt < 8; ++nt) {
        int j = nt * 16 + ln;
        float bj = cqab[j];
#pragma unroll
        for (int r = 0; r < 4; ++r) Sl[(w * 16 + quad * 4 + r) * 136 + j] = f2b(accF[nt][r] + bj);
    }
    // ---- out = relu(feats @ ccW[:, :128].T + pc) ----
    float4v accO[8];
#pragma unroll
    for (int ot = 0; ot < 8; ++ot) accO[ot] = (float4v){0.f, 0.f, 0.f, 0.f};
#pragma unroll
    for (int ks = 0; ks < 4; ++ks) {
        short8 a2 = *(const short8*)(Sl + myrow + ks * 32 + quad * 8);
#pragma unroll
        for (int ot = 0; ot < 8; ++ot) {
            short8 bw = *(const short8*)(ccWp + (((size_t)(ot * 4 + ks)) << 9) + lane * 8);
            accO[ot] = MFMA16(a2, bw, accO[ot]);
        }
    }
#pragma unroll
    for (int ot = 0; ot < 8; ++ot) {
        int o = ot * 16 + ln;
        float pco = pc[b * 128 + o];
#pragma unroll
        for (int r = 0; r < 4; ++r) {
            int c = c0 + quad * 4 + r;
            out[((size_t)(b * 2048 + c) << 7) + o] = fmaxf(accO[ot][r] + pco, 0.f);
        }
    }
}

extern "C" void kernel_launch(void* const* d_in, const int* in_sizes, int n_in, void* d_out, int out_size, void* d_ws,
                              size_t ws_size, hipStream_t stream) {
    const float* vf = (const float*)d_in[0];
    const float* qf = (const float*)d_in[1];
    const float* vmask = (const float*)d_in[2];
    const float* qmask = (const float*)d_in[3];
    const float* w4C = (const float*)d_in[4];
    const float* w4Q = (const float*)d_in[5];
    const float* w4mlu = (const float*)d_in[6];
    const float* cqaW = (const float*)d_in[7];
    const float* cqab = (const float*)d_in[8];
    const float* wp = (const float*)d_in[9];
    const float* ccW = (const float*)d_in[10];
    const float* ccb = (const float*)d_in[11];
    float* out = (float*)d_out;
    char* ws = (char*)d_ws;

    // workspace layout (~83 MB)
    size_t o = 0;
    short* vfA = (short*)(ws + o); o += 64ull * 2048 * 128 * 2;   // 33.5 MB
    short* vfT = (short*)(ws + o); o += 64ull * 2048 * 128 * 2;   // 33.5 MB
    short* qfBW = (short*)(ws + o); o += 64ull * 128 * 128 * 2;   // 2 MB
    short* qTf = (short*)(ws + o); o += 64ull * 128 * 128 * 2;    // 2 MB
    short* Ttf = (short*)(ws + o); o += 64ull * 128 * 128 * 2;    // 2 MB
    short* cqaWp = (short*)(ws + o); o += 128ull * 512 * 2;       // 128 KB
    short* ccWp = (short*)(ws + o); o += 128ull * 128 * 2;        // 32 KB
    float* Pg = (float*)(ws + o); o += 2ull * 64 * 128 * 128 * 4; // 8.4 MB
    float* Csg = (float*)(ws + o); o += 2ull * 64 * 128 * 4;      // 64 KB
    float* cvp = (float*)(ws + o); o += 64ull * 2048 * 4;         // 512 KB
    float* qvp = (float*)(ws + o); o += 64ull * 128 * 4;
    float* pc = (float*)(ws + o); o += 64ull * 128 * 4;

    k_packfuse<<<dim3(64, 64), 256, 0, stream>>>(vf, nullptr, w4C, vmask, vfA, vfT, cvp, 64);
    k_packfuse<<<dim3(4, 64), 256, 0, stream>>>(qf, w4mlu, w4Q, qmask, qfBW, qTf, qvp, 4);
    k_packW<<<32, 256, 0, stream>>>(cqaW, cqaWp);
    k_packWc<<<8, 256, 0, stream>>>(ccW, ccWp);
    k_pool<<<64, 128, 0, stream>>>(qf, qmask, wp, ccW, ccb, pc);
    k_Tacc<<<1024, 256, 0, stream>>>(vfA, vfT, qfBW, cvp, Pg, Csg);
    k_Tcomb<<<512, 256, 0, stream>>>(Pg, Csg, Ttf);
    k_out<<<2048, 256, 0, stream>>>(vfA, qfBW, qTf, Ttf, qvp, cqaWp, cqab, ccWp, pc, out);
}